// Round 8
// baseline (2208.532 us; speedup 1.0000x reference)
//
#include <hip/hip_runtime.h>
#include <hip/hip_cooperative_groups.h>
#include <hip/hip_bf16.h>

namespace cg = cooperative_groups;

typedef __hip_bfloat16 bf16;
typedef float v2f __attribute__((ext_vector_type(2)));

#define LEN 1024
#define N2 2048            // B * L rows
#define SCALE_L2E 0.5100697918f   // (1/sqrt(8)) * log2(e)

// ---- converted-input float offsets in ws ----
#define I_SCTX   0
#define I_FCTX   4096
#define I_STEST  6144
#define I_OBS    10240
#define I_EW1    10248
#define I_EB1    12040
#define I_EW2    12296
#define I_EB2    28680
#define I_WQ     28744
#define I_BQ     53320
#define I_WK     53704
#define I_BK     78280
#define I_WV     78664
#define I_BV     103240
#define I_WO     103624
#define I_BO     128200
#define I_FW1    128584
#define I_FB1    177736
#define I_FW2    178504
#define I_FB2    227656
#define I_BW1    228040
#define I_BB1    228136
#define I_BW2    228232
#define I_BB2    229000
#define I_NS     229048
#define I_NB     229432
#define I_FNS    229816
#define I_FNB    229880
#define I_HW1    229944
#define I_HB1    238136
#define I_HW2    238264
#define I_HB2    238520

#define OFF_FLAG 240000
#define OFF_PW   240256    // 6 layers x 288 floats: [17][8] (slope,inter)*log2e + 16 sorted bps
#define OFF_QVS  262144
#define OFF_KVS  393216
#define OFF_Q1   524288
#define OFF_Q2   655360
#define OFF_KB   786432
#define OFF_VB   917504
#define OFF_PART 1048576   // partials: [z=4][row=1024][h=8][ks=4][12] floats

__constant__ int C_OFFS[33] = {
    0, 4096, 6144, 10240, 10248, 12040, 12296, 28680, 28744, 53320, 53704,
    78280, 78664, 103240, 103624, 128200, 128584, 177736, 178504, 227656,
    228040, 228136, 228232, 229000, 229048, 229432, 229816, 229880, 229944,
    238136, 238264, 238520, 238522 };

struct InPtrs { const void* p[32]; };

__device__ __forceinline__ int get_isbf(const void* ns) {
    return (*(const unsigned*)ns == 0x3F803F80u) ? 1 : 0;
}

// ============================================================================
// Persistent cooperative kernel: all phases in one dispatch, grid.sync between.
// grid 1024 x 256 (4 blocks/CU co-resident: LDS 35.9KB, VGPR <= 128).
// ============================================================================
__global__ __launch_bounds__(256, 4) void k_mega(InPtrs ptrs, float* ws, void* out_raw) {
    __shared__ float smem[8976];                     // 35904 B, phase-aliased
    cg::grid_group grid = cg::this_grid();
    const int bid = blockIdx.x, t = threadIdx.x;
    const int isbf = get_isbf(ptrs.p[24]);

    // ---------------- P0: convert inputs (all blocks, flat) ----------------
    {
        int j = bid * 256 + t;
        if (j < 238522) {
            int i = 0;
            while (j >= C_OFFS[i + 1]) ++i;
            const void* src = ptrs.p[i];
            int jj = j - C_OFFS[i];
            ws[j] = isbf ? __bfloat162float(((const bf16*)src)[jj])
                         : ((const float*)src)[jj];
        }
    }
    // ---------------- P0b: piecewise bias tables (blocks 0..5) ----------------
    if (bid < 6) {
        const int L = bid;
        float* w1s = smem; float* b1s = smem + 16; float* bps = smem + 32;
        int* rnk = (int*)(smem + 48);
        auto cv = [&](const void* p, int idx) -> float {
            return isbf ? __bfloat162float(((const bf16*)p)[idx]) : ((const float*)p)[idx];
        };
        if (t == 0 && L == 0) ((int*)(ws + OFF_FLAG))[0] = isbf;
        if (t < 16) {
            float w = cv(ptrs.p[20], L * 16 + t), b0 = cv(ptrs.p[21], L * 16 + t);
            w1s[t] = w; b1s[t] = b0;
            bps[t] = (w != 0.f) ? (-b0 / w) : 1e30f;
        }
        __syncthreads();
        if (t < 16) {
            float me = bps[t]; int r = 0;
            for (int j = 0; j < 16; ++j) {
                float o = bps[j];
                if (o < me || (o == me && j < t)) ++r;
            }
            rnk[t] = r;
        }
        __syncthreads();
        if (t < 16) ws[OFF_PW + L * 288 + 272 + rnk[t]] = bps[t];
        if (t < 136) {
            int s = t >> 3, h = t & 7;
            float slope = 0.f, inter = cv(ptrs.p[23], L * 8 + h);
            for (int j = 0; j < 16; ++j) {
                float w = w1s[j];
                bool act = (w > 0.f) ? (rnk[j] < s)
                         : (w < 0.f) ? (rnk[j] >= s)
                                     : (b1s[j] > 0.f);
                if (act) {
                    float w2v = cv(ptrs.p[22], L * 128 + j * 8 + h);
                    slope += w * w2v;
                    inter += b1s[j] * w2v;
                }
            }
            const float LOG2E = 1.4426950408889634f;
            ws[OFF_PW + L * 288 + (s * 8 + h) * 2]     = slope * LOG2E;
            ws[OFF_PW + L * 288 + (s * 8 + h) * 2 + 1] = inter * LOG2E;
        }
    }
    grid.sync();

    // ---------------- P1: embed MLP + layer-0 QKV (2 rows/block) ----------------
    {
        float* hbuf = smem;            // [4][256]  c = row*2 + which (0=ctx,1=test)
        float* red  = smem + 1024;     // [4][256]
        float* xsA  = smem + 2048;     // [4][64]
        const int r0 = bid * 2;
        float in_[4][7];
#pragma unroll
        for (int row = 0; row < 2; ++row) {
            int r = r0 + row;
            const float* obc = ws + I_OBS + 4;
            const float* obu = ws + I_OBS;
            float* ic = in_[row * 2], * it = in_[row * 2 + 1];
            ic[0] = obc[0]; ic[1] = obc[1]; ic[2] = obc[2]; ic[3] = obc[3];
            it[0] = obu[0]; it[1] = obu[1]; it[2] = obu[2]; it[3] = obu[3];
            ic[4] = ws[I_SCTX + r * 2]; ic[5] = ws[I_SCTX + r * 2 + 1];
            it[4] = ws[I_STEST + r * 2]; it[5] = ws[I_STEST + r * 2 + 1];
            ic[6] = ws[I_FCTX + r]; it[6] = 0.f;
        }
        float a[4];
        {
            float b1v = ws[I_EB1 + t];
            a[0] = a[1] = a[2] = a[3] = b1v;
        }
#pragma unroll
        for (int i = 0; i < 7; ++i) {
            float w = ws[I_EW1 + i * 256 + t];
#pragma unroll
            for (int c = 0; c < 4; ++c) a[c] += in_[c][i] * w;
        }
#pragma unroll
        for (int c = 0; c < 4; ++c) hbuf[c * 256 + t] = fmaxf(a[c], 0.f);
        __syncthreads();
        {
            int d = t & 63, p = t >> 6;
            float s2[4] = {0.f, 0.f, 0.f, 0.f};
#pragma unroll 8
            for (int j = p * 64; j < p * 64 + 64; ++j) {
                float w = ws[I_EW2 + j * 64 + d];
#pragma unroll
                for (int c = 0; c < 4; ++c) s2[c] += hbuf[c * 256 + j] * w;
            }
#pragma unroll
            for (int c = 0; c < 4; ++c) red[c * 256 + t] = s2[c];
        }
        __syncthreads();
        {
            int c = t >> 6, d2 = t & 63;
            float o = red[c * 256 + d2] + red[c * 256 + 64 + d2]
                    + red[c * 256 + 128 + d2] + red[c * 256 + 192 + d2] + ws[I_EB2 + d2];
            int row = c >> 1, which = c & 1; int r = r0 + row;
            if (which == 0) ws[OFF_KVS + r * 64 + d2] = o;
            else            ws[OFF_QVS + r * 64 + d2] = o;
            xsA[c * 64 + d2] = o;
        }
        __syncthreads();
        {   // layer-0 QKV: o4 = Q1(test), Q2(ctx), KB(ctx), VB(ctx)
            int o4 = t >> 6, d = t & 63;
            const float* W; const float* bbp; int dsto;
            if (o4 == 0)      { W = ws + I_WQ; bbp = ws + I_BQ; dsto = OFF_Q1; }
            else if (o4 == 1) { W = ws + I_WQ; bbp = ws + I_BQ; dsto = OFF_Q2; }
            else if (o4 == 2) { W = ws + I_WK; bbp = ws + I_BK; dsto = OFF_KB; }
            else              { W = ws + I_WV; bbp = ws + I_BV; dsto = OFF_VB; }
            int whichx = (o4 == 0) ? 1 : 0;
            float acc0 = bbp[d], acc1 = acc0;
#pragma unroll 8
            for (int k = 0; k < 64; ++k) {
                float w = W[k * 64 + d];
                acc0 += xsA[(0 + whichx) * 64 + k] * w;
                acc1 += xsA[(2 + whichx) * 64 + k] * w;
            }
            ws[dsto + r0 * 64 + d]       = acc0;
            ws[dsto + (r0 + 1) * 64 + d] = acc1;
        }
    }
    grid.sync();

    // ---------------- 6 layers: attention phase + fuse phase ----------------
    for (int blk = 0; blk < 6; ++blk) {
        // ===== attention (R6 structure: broadcast K/V, bias[32][132], 2q/thread)
        {
            float* Ks  = smem;            // 32 x 68
            float* Vs  = smem + 2176;
            float* bbf = smem + 4352;     // bias [32][132]; pw at 4224; merge overlay
            v2f* pw = (v2f*)&bbf[4224];

            const int z = bid & 3, ks = (bid >> 2) & 3, qt = bid >> 4;
            const int b = z & 1, kind = z >> 1;
            const int q0 = qt * 16;
            const float* Qbuf = ws + (kind == 0 ? OFF_Q1 : OFF_Q2);
            const float* Kbuf = ws + OFF_KB;
            const float* Vbuf = ws + OFF_VB;
            const float* sq_src = ws + (kind == 0 ? I_STEST : I_SCTX);
            const float* sk_src = ws + I_SCTX;
            const float* pwg = ws + OFF_PW + blk * 288;

            float bp[16];
#pragma unroll
            for (int j = 0; j < 16; ++j) bp[j] = pwg[272 + j];

            if (t < 136) pw[t] = (v2f){ pwg[t * 2], pwg[t * 2 + 1] };

            const int h    = t & 7;
            const int qg   = (t >> 3) & 7;
            const int ksub = t >> 6;

            v2f qf[2][4];
#pragma unroll
            for (int qq = 0; qq < 2; ++qq) {
                const float* qp = Qbuf + (b * LEN + q0 + qg * 2 + qq) * 64 + h * 8;
                float4 qa = *(const float4*)qp;
                float4 qb = *(const float4*)(qp + 4);
                qf[qq][0] = (v2f){qa.x, qa.y}; qf[qq][1] = (v2f){qa.z, qa.w};
                qf[qq][2] = (v2f){qb.x, qb.y}; qf[qq][3] = (v2f){qb.z, qb.w};
            }
            float sqx, sqy;
            {
                const float* sp = sq_src + (b * LEN + q0 + (t >> 4)) * 2;
                sqx = sp[0]; sqy = sp[1];
            }

            float lsum[2] = {0.f, 0.f};
            v2f oacc[2][4] = {};

            const int kt0 = ks * 8, kt1 = kt0 + 8;
            const int kr = t >> 3, jc = (t & 7) * 8;

            float4 ka0, ka1, va0, va1;
            {
                const float* ksrc = Kbuf + (b * LEN + kt0 * 32 + kr) * 64 + jc;
                const float* vsrc = Vbuf + (b * LEN + kt0 * 32 + kr) * 64 + jc;
                ka0 = *(const float4*)ksrc; ka1 = *(const float4*)(ksrc + 4);
                va0 = *(const float4*)vsrc; va1 = *(const float4*)(vsrc + 4);
            }

            for (int kt = kt0; kt < kt1; ++kt) {
                __syncthreads();
                *(float4*)&Ks[kr * 68 + jc]     = ka0;
                *(float4*)&Ks[kr * 68 + jc + 4] = ka1;
                *(float4*)&Vs[kr * 68 + jc]     = va0;
                *(float4*)&Vs[kr * 68 + jc + 4] = va1;
                {   // bias precompute: keys kp, kp+16 of query qs -> bbf[k][132] rows
                    int qs = t >> 4, kp = t & 15;
                    const float* c0 = sk_src + (b * LEN + kt * 32 + kp) * 2;
                    float2 kc0 = *(const float2*)c0;
                    float2 kc1 = *(const float2*)(c0 + 32);
                    float dx0 = sqx - kc0.x, dy0 = sqy - kc0.y;
                    float dx1 = sqx - kc1.x, dy1 = sqy - kc1.y;
                    float d0 = dx0 * dx0 + dy0 * dy0;
                    float d1 = dx1 * dx1 + dy1 * dy1;
                    int s0 = 0, s1 = 0;
#pragma unroll
                    for (int j = 0; j < 16; ++j) { s0 += (d0 > bp[j]); s1 += (d1 > bp[j]); }
                    const float* p0 = (const float*)(pw + s0 * 8);
                    const float* p1 = (const float*)(pw + s1 * 8);
                    float* bd0 = &bbf[kp * 132 + qs * 8];
                    float* bd1 = &bbf[(kp + 16) * 132 + qs * 8];
                    {
                        float4 a0 = *(const float4*)p0,       a1 = *(const float4*)(p0 + 4);
                        float4 a2 = *(const float4*)(p0 + 8), a3 = *(const float4*)(p0 + 12);
                        *(float4*)bd0       = make_float4(fmaf(a0.x, d0, a0.y), fmaf(a0.z, d0, a0.w),
                                                          fmaf(a1.x, d0, a1.y), fmaf(a1.z, d0, a1.w));
                        *(float4*)(bd0 + 4) = make_float4(fmaf(a2.x, d0, a2.y), fmaf(a2.z, d0, a2.w),
                                                          fmaf(a3.x, d0, a3.y), fmaf(a3.z, d0, a3.w));
                    }
                    {
                        float4 a0 = *(const float4*)p1,       a1 = *(const float4*)(p1 + 4);
                        float4 a2 = *(const float4*)(p1 + 8), a3 = *(const float4*)(p1 + 12);
                        *(float4*)bd1       = make_float4(fmaf(a0.x, d1, a0.y), fmaf(a0.z, d1, a0.w),
                                                          fmaf(a1.x, d1, a1.y), fmaf(a1.z, d1, a1.w));
                        *(float4*)(bd1 + 4) = make_float4(fmaf(a2.x, d1, a2.y), fmaf(a2.z, d1, a2.w),
                                                          fmaf(a3.x, d1, a3.y), fmaf(a3.z, d1, a3.w));
                    }
                }
                __syncthreads();

                if (kt + 1 < kt1) {
                    const float* ksrc = Kbuf + (b * LEN + (kt + 1) * 32 + kr) * 64 + jc;
                    const float* vsrc = Vbuf + (b * LEN + (kt + 1) * 32 + kr) * 64 + jc;
                    ka0 = *(const float4*)ksrc; ka1 = *(const float4*)(ksrc + 4);
                    va0 = *(const float4*)vsrc; va1 = *(const float4*)(vsrc + 4);
                }

                const float* Kb = &Ks[(ksub * 8) * 68 + h * 8];
                const float* Vb = &Vs[(ksub * 8) * 68 + h * 8];
                const float* Bb = &bbf[(ksub * 8) * 132 + qg * 16 + h];
#pragma unroll
                for (int k8 = 0; k8 < 8; ++k8) {
                    const v2f* kf = (const v2f*)(Kb + k8 * 68);
                    v2f k0 = kf[0], k1 = kf[1], k2v = kf[2], k3 = kf[3];
                    const v2f* vf = (const v2f*)(Vb + k8 * 68);
                    v2f v0 = vf[0], v1 = vf[1], v2v = vf[2], v3 = vf[3];
#pragma unroll
                    for (int qq = 0; qq < 2; ++qq) {
                        float bv = Bb[k8 * 132 + qq * 8];
                        v2f a = qf[qq][0] * k0;
                        a += qf[qq][1] * k1;
                        a += qf[qq][2] * k2v;
                        a += qf[qq][3] * k3;
                        float sv = fmaf(a.x + a.y, SCALE_L2E, bv);
                        float p = exp2f(sv);
                        lsum[qq] += p;
                        v2f pp = (v2f){p, p};
                        oacc[qq][0] += pp * v0;
                        oacc[qq][1] += pp * v1;
                        oacc[qq][2] += pp * v2v;
                        oacc[qq][3] += pp * v3;
                    }
                }
            }

            // merge ksub quartet via LDS overlay, write UNNORMALIZED partial
            __syncthreads();
            if (ksub) {
#pragma unroll
                for (int qq = 0; qq < 2; ++qq) {
                    float* p = &bbf[((((ksub - 1) * 16) + qg * 2 + qq) * 8 + h) * 12];
                    *(float4*)p       = make_float4(oacc[qq][0].x, oacc[qq][0].y, oacc[qq][1].x, oacc[qq][1].y);
                    *(float4*)(p + 4) = make_float4(oacc[qq][2].x, oacc[qq][2].y, oacc[qq][3].x, oacc[qq][3].y);
                    p[8] = lsum[qq];
                }
            }
            __syncthreads();
            if (ksub == 0) {
#pragma unroll
                for (int qq = 0; qq < 2; ++qq) {
                    int q = qg * 2 + qq;
                    float ov[8] = { oacc[qq][0].x, oacc[qq][0].y, oacc[qq][1].x, oacc[qq][1].y,
                                    oacc[qq][2].x, oacc[qq][2].y, oacc[qq][3].x, oacc[qq][3].y };
                    float lq = lsum[qq];
#pragma unroll
                    for (int m = 0; m < 3; ++m) {
                        const float* p = &bbf[((m * 16 + q) * 8 + h) * 12];
                        float4 m0 = *(const float4*)p, m1 = *(const float4*)(p + 4);
                        ov[0] += m0.x; ov[1] += m0.y; ov[2] += m0.z; ov[3] += m0.w;
                        ov[4] += m1.x; ov[5] += m1.y; ov[6] += m1.z; ov[7] += m1.w;
                        lq += p[8];
                    }
                    float* pp = ws + OFF_PART + (z * LEN + q0 + q) * 384 + (h * 4 + ks) * 12;
                    *(float4*)(pp)     = make_float4(ov[0], ov[1], ov[2], ov[3]);
                    *(float4*)(pp + 4) = make_float4(ov[4], ov[5], ov[6], ov[7]);
                    *(float4*)(pp + 8) = make_float4(lq, 0.f, 0.f, 0.f);
                }
            }
        }
        grid.sync();

        // ===== fuse: partial-merge + Wo + LN + FFN + LN + next-QKV
        // 256 threads = 2 kinds x (2 waves); tl in [0,128) per kind
        {
            const int kind = t >> 7, tl = t & 127;
            float* raw = smem + kind * 768;          // [768]
            float* xo  = smem + 1536 + kind * 128;   // [2][64]
            float* xs  = smem + 1792 + kind * 128;   // [2][64]
            float* hs  = smem + 2048 + kind * 256;   // [2][128]
            float* xn  = smem + 2560 + kind * 128;   // [2][64]
            const int r0 = bid * 2;
            const int b = r0 >> 10, row0 = r0 & 1023;
            const int z = kind * 2 + b;
            const int half = tl >> 6, tt = tl & 63;
            float* io = ws + (kind == 0 ? OFF_QVS : OFF_KVS);

            const float* pbase = ws + OFF_PART + (z * LEN + row0) * 384;
            *(float4*)&raw[tl * 4] = *(const float4*)&pbase[tl * 4];
            if (tl < 64) *(float4*)&raw[512 + tl * 4] = *(const float4*)&pbase[512 + tl * 4];
            __syncthreads();

            {   // merge 4 K-split partials
                int h = tt >> 3, d = tt & 7;
                const float* rw = raw + half * 384;
                float L = 0.f, o = 0.f;
#pragma unroll
                for (int k2 = 0; k2 < 4; ++k2) {
                    L += rw[(h * 4 + k2) * 12 + 8];
                    o += rw[(h * 4 + k2) * 12 + d];
                }
                xo[half * 64 + tt] = o / L;
            }
            __syncthreads();

            {   // Wo + residual + LN
                const float* Wo = ws + I_WO + blk * 4096;
                float acc = ws[I_BO + blk * 64 + tt];
#pragma unroll 8
                for (int j = 0; j < 64; ++j) acc += xo[half * 64 + j] * Wo[j * 64 + tt];
                acc += io[(r0 + half) * 64 + tt];
                float s = acc, ss2 = acc * acc;
#pragma unroll
                for (int off = 1; off < 64; off <<= 1) { s += __shfl_xor(s, off); ss2 += __shfl_xor(ss2, off); }
                float mu_ = s * (1.f / 64.f);
                float var_ = ss2 * (1.f / 64.f) - mu_ * mu_;
                float rs_ = rsqrtf(fmaxf(var_, 0.f) + 1e-6f);
                xs[half * 64 + tt] = (acc - mu_) * rs_ * ws[I_NS + blk * 64 + tt] + ws[I_NB + blk * 64 + tt];
            }
            __syncthreads();

            {   // FFN hidden: tl = column, both rows
                const float* W1 = ws + I_FW1 + blk * 8192;
                float a0 = ws[I_FB1 + blk * 128 + tl], a1 = a0;
#pragma unroll 8
                for (int k = 0; k < 64; ++k) {
                    float w = W1[k * 128 + tl];
                    a0 += xs[k] * w;
                    a1 += xs[64 + k] * w;
                }
                hs[tl] = fmaxf(a0, 0.f);
                hs[128 + tl] = fmaxf(a1, 0.f);
            }
            __syncthreads();

            {   // FFN out + residual + LN
                const float* W2 = ws + I_FW2 + blk * 8192;
                float a2 = ws[I_FB2 + blk * 64 + tt];
#pragma unroll 8
                for (int k = 0; k < 128; ++k) a2 += hs[half * 128 + k] * W2[k * 64 + tt];
                a2 += xs[half * 64 + tt];
                float s = a2, ss2 = a2 * a2;
#pragma unroll
                for (int off = 1; off < 64; off <<= 1) { s += __shfl_xor(s, off); ss2 += __shfl_xor(ss2, off); }
                float mu_ = s * (1.f / 64.f);
                float var_ = ss2 * (1.f / 64.f) - mu_ * mu_;
                float rs_ = rsqrtf(fmaxf(var_, 0.f) + 1e-6f);
                float outv = (a2 - mu_) * rs_ * ws[I_NS + blk * 64 + tt] + ws[I_NB + blk * 64 + tt];
                io[(r0 + half) * 64 + tt] = outv;
                xn[half * 64 + tt] = outv;
            }
            __syncthreads();

            if (blk < 5) {   // next-layer QKV
                const int nb_ = blk + 1;
                if (kind == 0) {
                    const float* W = ws + I_WQ + nb_ * 4096;
                    float acc = ws[I_BQ + nb_ * 64 + tt];
#pragma unroll 8
                    for (int k = 0; k < 64; ++k) acc += xn[half * 64 + k] * W[k * 64 + tt];
                    ws[OFF_Q1 + (r0 + half) * 64 + tt] = acc;
                } else {
                    {
                        const float* W  = ws + (half == 0 ? I_WQ : I_WK) + nb_ * 4096;
                        const float* bbp = ws + (half == 0 ? I_BQ : I_BK) + nb_ * 64;
                        float* dst = ws + (half == 0 ? OFF_Q2 : OFF_KB);
                        float acc0 = bbp[tt], acc1 = acc0;
#pragma unroll 8
                        for (int k = 0; k < 64; ++k) {
                            float w = W[k * 64 + tt];
                            acc0 += xn[k] * w;
                            acc1 += xn[64 + k] * w;
                        }
                        dst[r0 * 64 + tt]       = acc0;
                        dst[(r0 + 1) * 64 + tt] = acc1;
                    }
                    {
                        const float* Wv = ws + I_WV + nb_ * 4096;
                        float accv = ws[I_BV + nb_ * 64 + tt];
#pragma unroll 8
                        for (int k = 0; k < 64; ++k) accv += xn[half * 64 + k] * Wv[k * 64 + tt];
                        ws[OFF_VB + (r0 + half) * 64 + tt] = accv;
                    }
                }
            }
        }
        grid.sync();
    }

    // ---------------- head: final LN + head MLP (2 rows/block) ----------------
    {
        float* xl = smem;        // [2][64]
        float* hl = smem + 128;  // [2][128]
        const int row = t >> 7, tl = t & 127;
        const int r = bid * 2 + row;
        if (tl < 64) {
            float v = ws[OFF_QVS + r * 64 + tl];
            float s = v, ss2 = v * v;
#pragma unroll
            for (int off = 1; off < 64; off <<= 1) { s += __shfl_xor(s, off); ss2 += __shfl_xor(ss2, off); }
            float mu_ = s * (1.f / 64.f);
            float var_ = ss2 * (1.f / 64.f) - mu_ * mu_;
            float rs_ = rsqrtf(fmaxf(var_, 0.f) + 1e-6f);
            xl[row * 64 + tl] = (v - mu_) * rs_ * ws[I_FNS + tl] + ws[I_FNB + tl];
        }
        __syncthreads();
        float acc = ws[I_HB1 + tl];
#pragma unroll 8
        for (int k = 0; k < 64; ++k) acc += xl[row * 64 + k] * ws[I_HW1 + k * 128 + tl];
        hl[row * 128 + tl] = fmaxf(acc, 0.f);
        __syncthreads();
        if (tl < 2) {
            float a = ws[I_HB2 + tl];
            for (int j = 0; j < 128; ++j) a += hl[row * 128 + j] * ws[I_HW2 + j * 2 + tl];
            float v = (tl == 0) ? a : __expf(a * 0.5f);
            int idx = (tl == 0) ? r : (N2 + r);
            if (isbf) ((bf16*)out_raw)[idx] = __float2bfloat16(v);
            else      ((float*)out_raw)[idx] = v;
        }
    }
}

// ============================================================================
// Fallback path: the proven R6 kernel sequence (used only if cooperative
// launch is unavailable).
// ============================================================================
__global__ __launch_bounds__(256) void k_pwf(InPtrs ptrs, float* ws) {
    const int L = blockIdx.x, t = threadIdx.x;
    __shared__ float w1s[16], b1s[16], bps[16];
    __shared__ int rnk[16];
    __shared__ int sflag;
    if (t == 0) {
        int f = get_isbf(ptrs.p[24]);
        sflag = f;
        if (L == 0) ((int*)(ws + OFF_FLAG))[0] = f;
    }
    __syncthreads();
    const int isbf = sflag;
    auto cv = [&](const void* p, int idx) -> float {
        return isbf ? __bfloat162float(((const bf16*)p)[idx]) : ((const float*)p)[idx];
    };
    if (t < 16) {
        float w = cv(ptrs.p[20], L * 16 + t), b0 = cv(ptrs.p[21], L * 16 + t);
        w1s[t] = w; b1s[t] = b0;
        bps[t] = (w != 0.f) ? (-b0 / w) : 1e30f;
    }
    __syncthreads();
    if (t < 16) {
        float me = bps[t]; int r = 0;
        for (int j = 0; j < 16; ++j) {
            float o = bps[j];
            if (o < me || (o == me && j < t)) ++r;
        }
        rnk[t] = r;
    }
    __syncthreads();
    if (t < 16) ws[OFF_PW + L * 288 + 272 + rnk[t]] = bps[t];
    if (t < 136) {
        int s = t >> 3, h = t & 7;
        float slope = 0.f, inter = cv(ptrs.p[23], L * 8 + h);
        for (int j = 0; j < 16; ++j) {
            float w = w1s[j];
            bool act = (w > 0.f) ? (rnk[j] < s)
                     : (w < 0.f) ? (rnk[j] >= s)
                                 : (b1s[j] > 0.f);
            if (act) {
                float w2v = cv(ptrs.p[22], L * 128 + j * 8 + h);
                slope += w * w2v;
                inter += b1s[j] * w2v;
            }
        }
        const float LOG2E = 1.4426950408889634f;
        ws[OFF_PW + L * 288 + (s * 8 + h) * 2]     = slope * LOG2E;
        ws[OFF_PW + L * 288 + (s * 8 + h) * 2 + 1] = inter * LOG2E;
    }
}

__global__ __launch_bounds__(256) void k_cvt(InPtrs ptrs, float* ws) {
    __shared__ int sflag;
    if (threadIdx.x == 0) sflag = ((const int*)(ws + OFF_FLAG))[0];
    __syncthreads();
    const int isbf = sflag;
    const int i = blockIdx.y;
    const int o0 = C_OFFS[i], n = C_OFFS[i + 1] - o0;
    const void* src = ptrs.p[i];
    for (int j = blockIdx.x * 256 + threadIdx.x; j < n; j += gridDim.x * 256) {
        float v = isbf ? __bfloat162float(((const bf16*)src)[j])
                       : ((const float*)src)[j];
        ws[o0 + j] = v;
    }
}

__global__ __launch_bounds__(256) void k_emq(float* ws) {
    __shared__ float hbuf[2][256];
    __shared__ float red[2][256];
    __shared__ float xs[2][64];
    int r = blockIdx.x, t = threadIdx.x;

    float inc[7], int_[7];
    {
        const float* obc = ws + I_OBS + 4;
        const float* obu = ws + I_OBS;
        inc[0] = obc[0]; inc[1] = obc[1]; inc[2] = obc[2]; inc[3] = obc[3];
        int_[0] = obu[0]; int_[1] = obu[1]; int_[2] = obu[2]; int_[3] = obu[3];
        inc[4] = ws[I_SCTX + r * 2]; inc[5] = ws[I_SCTX + r * 2 + 1];
        int_[4] = ws[I_STEST + r * 2]; int_[5] = ws[I_STEST + r * 2 + 1];
        inc[6] = ws[I_FCTX + r]; int_[6] = 0.f;
    }
    float ac = ws[I_EB1 + t], at = ac;
#pragma unroll
    for (int i = 0; i < 7; ++i) {
        float w = ws[I_EW1 + i * 256 + t];
        ac += inc[i] * w; at += int_[i] * w;
    }
    hbuf[0][t] = fmaxf(ac, 0.f);
    hbuf[1][t] = fmaxf(at, 0.f);
    __syncthreads();

    int d = t & 63, p = t >> 6;
    float a0 = 0.f, a1 = 0.f;
#pragma unroll 8
    for (int j = p * 64; j < p * 64 + 64; ++j) {
        float w = ws[I_EW2 + j * 64 + d];
        a0 += hbuf[0][j] * w; a1 += hbuf[1][j] * w;
    }
    red[0][t] = a0; red[1][t] = a1;
    __syncthreads();
    if (t < 128) {
        int which = t >> 6, d2 = t & 63;
        float o = red[which][d2] + red[which][64 + d2] + red[which][128 + d2]
                + red[which][192 + d2] + ws[I_EB2 + d2];
        if (which == 0) { ws[OFF_KVS + r * 64 + d2] = o; xs[1][d2] = o; }
        else            { ws[OFF_QVS + r * 64 + d2] = o; xs[0][d2] = o; }
    }
    __syncthreads();

    int o = t >> 6;
    const float* x = (o == 0) ? xs[0] : xs[1];
    const float* W; const float* bb; float* dst;
    if (o <= 1)      { W = ws + I_WQ; bb = ws + I_BQ; dst = ws + (o == 0 ? OFF_Q1 : OFF_Q2); }
    else if (o == 2) { W = ws + I_WK; bb = ws + I_BK; dst = ws + OFF_KB; }
    else             { W = ws + I_WV; bb = ws + I_BV; dst = ws + OFF_VB; }
    float acc = bb[d];
#pragma unroll 8
    for (int k = 0; k < 64; ++k) acc += x[k] * W[k * 64 + d];
    dst[r * 64 + d] = acc;
}

__global__ __launch_bounds__(256, 4) void k_attn(int blk, float* ws) {
    __shared__ float Ks[2176];
    __shared__ float Vs[2176];
    __shared__ float bbf[4624];
    v2f* pw = (v2f*)&bbf[4224];

    const int t = threadIdx.x;
    const int qt = blockIdx.x, ks = blockIdx.y, z = blockIdx.z;
    const int b = z & 1, kind = z >> 1;
    const int q0 = qt * 16;
    const float* Qbuf = ws + (kind == 0 ? OFF_Q1 : OFF_Q2);
    const float* Kbuf = ws + OFF_KB;
    const float* Vbuf = ws + OFF_VB;
    const float* sq_src = ws + (kind == 0 ? I_STEST : I_SCTX);
    const float* sk_src = ws + I_SCTX;
    const float* pwg = ws + OFF_PW + blk * 288;

    float bp[16];
#pragma unroll
    for (int j = 0; j < 16; ++j) bp[j] = pwg[272 + j];

    if (t < 136) pw[t] = (v2f){ pwg[t * 2], pwg[t * 2 + 1] };

    const int h    = t & 7;
    const int qg   = (t >> 3) & 7;
    const int ksub = t >> 6;

    v2f qf[2][4];
#pragma unroll
    for (int qq = 0; qq < 2; ++qq) {
        const float* qp = Qbuf + (b * LEN + q0 + qg * 2 + qq) * 64 + h * 8;
        float4 qa = *(const float4*)qp;
        float4 qb = *(const float4*)(qp + 4);
        qf[qq][0] = (v2f){qa.x, qa.y}; qf[qq][1] = (v2f){qa.z, qa.w};
        qf[qq][2] = (v2f){qb.x, qb.y}; qf[qq][3] = (v2f){qb.z, qb.w};
    }
    float sqx, sqy;
    {
        const float* sp = sq_src + (b * LEN + q0 + (t >> 4)) * 2;
        sqx = sp[0]; sqy = sp[1];
    }

    float lsum[2] = {0.f, 0.f};
    v2f oacc[2][4] = {};

    const int kt0 = ks * 8, kt1 = kt0 + 8;
    const int kr = t >> 3, jc = (t & 7) * 8;

    float4 ka0, ka1, va0, va1;
    {
        const float* ksrc = Kbuf + (b * LEN + kt0 * 32 + kr) * 64 + jc;
        const float* vsrc = Vbuf + (b * LEN + kt0 * 32 + kr) * 64 + jc;
        ka0 = *(const float4*)ksrc; ka1 = *(const float4*)(ksrc + 4);
        va0 = *(const float4*)vsrc; va1 = *(const float4*)(vsrc + 4);
    }

    for (int kt = kt0; kt < kt1; ++kt) {
        __syncthreads();
        *(float4*)&Ks[kr * 68 + jc]     = ka0;
        *(float4*)&Ks[kr * 68 + jc + 4] = ka1;
        *(float4*)&Vs[kr * 68 + jc]     = va0;
        *(float4*)&Vs[kr * 68 + jc + 4] = va1;
        {
            int qs = t >> 4, kp = t & 15;
            const float* c0 = sk_src + (b * LEN + kt * 32 + kp) * 2;
            float2 kc0 = *(const float2*)c0;
            float2 kc1 = *(const float2*)(c0 + 32);
            float dx0 = sqx - kc0.x, dy0 = sqy - kc0.y;
            float dx1 = sqx - kc1.x, dy1 = sqy - kc1.y;
            float d0 = dx0 * dx0 + dy0 * dy0;
            float d1 = dx1 * dx1 + dy1 * dy1;
            int s0 = 0, s1 = 0;
#pragma unroll
            for (int j = 0; j < 16; ++j) { s0 += (d0 > bp[j]); s1 += (d1 > bp[j]); }
            const float* p0 = (const float*)(pw + s0 * 8);
            const float* p1 = (const float*)(pw + s1 * 8);
            float* bd0 = &bbf[kp * 132 + qs * 8];
            float* bd1 = &bbf[(kp + 16) * 132 + qs * 8];
            {
                float4 a0 = *(const float4*)p0,       a1 = *(const float4*)(p0 + 4);
                float4 a2 = *(const float4*)(p0 + 8), a3 = *(const float4*)(p0 + 12);
                *(float4*)bd0       = make_float4(fmaf(a0.x, d0, a0.y), fmaf(a0.z, d0, a0.w),
                                                  fmaf(a1.x, d0, a1.y), fmaf(a1.z, d0, a1.w));
                *(float4*)(bd0 + 4) = make_float4(fmaf(a2.x, d0, a2.y), fmaf(a2.z, d0, a2.w),
                                                  fmaf(a3.x, d0, a3.y), fmaf(a3.z, d0, a3.w));
            }
            {
                float4 a0 = *(const float4*)p1,       a1 = *(const float4*)(p1 + 4);
                float4 a2 = *(const float4*)(p1 + 8), a3 = *(const float4*)(p1 + 12);
                *(float4*)bd1       = make_float4(fmaf(a0.x, d1, a0.y), fmaf(a0.z, d1, a0.w),
                                                  fmaf(a1.x, d1, a1.y), fmaf(a1.z, d1, a1.w));
                *(float4*)(bd1 + 4) = make_float4(fmaf(a2.x, d1, a2.y), fmaf(a2.z, d1, a2.w),
                                                  fmaf(a3.x, d1, a3.y), fmaf(a3.z, d1, a3.w));
            }
        }
        __syncthreads();

        if (kt + 1 < kt1) {
            const float* ksrc = Kbuf + (b * LEN + (kt + 1) * 32 + kr) * 64 + jc;
            const float* vsrc = Vbuf + (b * LEN + (kt + 1) * 32 + kr) * 64 + jc;
            ka0 = *(const float4*)ksrc; ka1 = *(const float4*)(ksrc + 4);
            va0 = *(const float4*)vsrc; va1 = *(const float4*)(vsrc + 4);
        }

        const float* Kb = &Ks[(ksub * 8) * 68 + h * 8];
        const float* Vb = &Vs[(ksub * 8) * 68 + h * 8];
        const float* Bb = &bbf[(ksub * 8) * 132 + qg * 16 + h];
#pragma unroll
        for (int k8 = 0; k8 < 8; ++k8) {
            const v2f* kf = (const v2f*)(Kb + k8 * 68);
            v2f k0 = kf[0], k1 = kf[1], k2v = kf[2], k3 = kf[3];
            const v2f* vf = (const v2f*)(Vb + k8 * 68);
            v2f v0 = vf[0], v1 = vf[1], v2v = vf[2], v3 = vf[3];
#pragma unroll
            for (int qq = 0; qq < 2; ++qq) {
                float bv = Bb[k8 * 132 + qq * 8];
                v2f a = qf[qq][0] * k0;
                a += qf[qq][1] * k1;
                a += qf[qq][2] * k2v;
                a += qf[qq][3] * k3;
                float sv = fmaf(a.x + a.y, SCALE_L2E, bv);
                float p = exp2f(sv);
                lsum[qq] += p;
                v2f pp = (v2f){p, p};
                oacc[qq][0] += pp * v0;
                oacc[qq][1] += pp * v1;
                oacc[qq][2] += pp * v2v;
                oacc[qq][3] += pp * v3;
            }
        }
    }

    __syncthreads();
    if (ksub) {
#pragma unroll
        for (int qq = 0; qq < 2; ++qq) {
            float* p = &bbf[((((ksub - 1) * 16) + qg * 2 + qq) * 8 + h) * 12];
            *(float4*)p       = make_float4(oacc[qq][0].x, oacc[qq][0].y, oacc[qq][1].x, oacc[qq][1].y);
            *(float4*)(p + 4) = make_float4(oacc[qq][2].x, oacc[qq][2].y, oacc[qq][3].x, oacc[qq][3].y);
            p[8] = lsum[qq];
        }
    }
    __syncthreads();
    if (ksub == 0) {
#pragma unroll
        for (int qq = 0; qq < 2; ++qq) {
            int q = qg * 2 + qq;
            float ov[8] = { oacc[qq][0].x, oacc[qq][0].y, oacc[qq][1].x, oacc[qq][1].y,
                            oacc[qq][2].x, oacc[qq][2].y, oacc[qq][3].x, oacc[qq][3].y };
            float lq = lsum[qq];
#pragma unroll
            for (int m = 0; m < 3; ++m) {
                const float* p = &bbf[((m * 16 + q) * 8 + h) * 12];
                float4 m0 = *(const float4*)p, m1 = *(const float4*)(p + 4);
                ov[0] += m0.x; ov[1] += m0.y; ov[2] += m0.z; ov[3] += m0.w;
                ov[4] += m1.x; ov[5] += m1.y; ov[6] += m1.z; ov[7] += m1.w;
                lq += p[8];
            }
            float* pp = ws + OFF_PART + (z * LEN + q0 + q) * 384 + (h * 4 + ks) * 12;
            *(float4*)(pp)     = make_float4(ov[0], ov[1], ov[2], ov[3]);
            *(float4*)(pp + 4) = make_float4(ov[4], ov[5], ov[6], ov[7]);
            *(float4*)(pp + 8) = make_float4(lq, 0.f, 0.f, 0.f);
        }
    }
}

__global__ __launch_bounds__(128) void k_fuse(int blk, float* ws) {
    __shared__ float raw[768];
    __shared__ float xo[2][64];
    __shared__ float xs[2][64];
    __shared__ float hs[2][128];
    __shared__ float xn[2][64];
    const int bx = blockIdx.x, kind = blockIdx.y, t = threadIdx.x;
    const int r0 = bx * 2;
    const int b = r0 >> 10, row0 = r0 & 1023;
    const int z = kind * 2 + b;
    const int half = t >> 6, tt = t & 63;
    float* io = ws + (kind == 0 ? OFF_QVS : OFF_KVS);

    const float* pbase = ws + OFF_PART + (z * LEN + row0) * 384;
    *(float4*)&raw[t * 4] = *(const float4*)&pbase[t * 4];
    if (t < 64) *(float4*)&raw[512 + t * 4] = *(const float4*)&pbase[512 + t * 4];
    __syncthreads();

    {
        int h = tt >> 3, d = tt & 7;
        const float* rw = raw + half * 384;
        float L = 0.f, o = 0.f;
#pragma unroll
        for (int k2 = 0; k2 < 4; ++k2) {
            L += rw[(h * 4 + k2) * 12 + 8];
            o += rw[(h * 4 + k2) * 12 + d];
        }
        xo[half][tt] = o / L;
    }
    __syncthreads();

    {
        const float* Wo = ws + I_WO + blk * 4096;
        float acc = ws[I_BO + blk * 64 + tt];
#pragma unroll 8
        for (int j = 0; j < 64; ++j) acc += xo[half][j] * Wo[j * 64 + tt];
        acc += io[(r0 + half) * 64 + tt];
        float s = acc, ss2 = acc * acc;
#pragma unroll
        for (int off = 1; off < 64; off <<= 1) { s += __shfl_xor(s, off); ss2 += __shfl_xor(ss2, off); }
        float mu_ = s * (1.f / 64.f);
        float var_ = ss2 * (1.f / 64.f) - mu_ * mu_;
        float rs_ = rsqrtf(fmaxf(var_, 0.f) + 1e-6f);
        xs[half][tt] = (acc - mu_) * rs_ * ws[I_NS + blk * 64 + tt] + ws[I_NB + blk * 64 + tt];
    }
    __syncthreads();

    {
        const float* W1 = ws + I_FW1 + blk * 8192;
        float a0 = ws[I_FB1 + blk * 128 + t], a1 = a0;
#pragma unroll 8
        for (int k = 0; k < 64; ++k) {
            float w = W1[k * 128 + t];
            a0 += xs[0][k] * w;
            a1 += xs[1][k] * w;
        }
        hs[0][t] = fmaxf(a0, 0.f);
        hs[1][t] = fmaxf(a1, 0.f);
    }
    __syncthreads();

    {
        const float* W2 = ws + I_FW2 + blk * 8192;
        float a2 = ws[I_FB2 + blk * 64 + tt];
#pragma unroll 8
        for (int k = 0; k < 128; ++k) a2 += hs[half][k] * W2[k * 64 + tt];
        a2 += xs[half][tt];
        float s = a2, ss2 = a2 * a2;
#pragma unroll
        for (int off = 1; off < 64; off <<= 1) { s += __shfl_xor(s, off); ss2 += __shfl_xor(ss2, off); }
        float mu_ = s * (1.f / 64.f);
        float var_ = ss2 * (1.f / 64.f) - mu_ * mu_;
        float rs_ = rsqrtf(fmaxf(var_, 0.f) + 1e-6f);
        float outv = (a2 - mu_) * rs_ * ws[I_NS + blk * 64 + tt] + ws[I_NB + blk * 64 + tt];
        io[(r0 + half) * 64 + tt] = outv;
        xn[half][tt] = outv;
    }
    __syncthreads();

    if (blk < 5) {
        const int nb_ = blk + 1;
        if (kind == 0) {
            const float* W = ws + I_WQ + nb_ * 4096;
            float acc = ws[I_BQ + nb_ * 64 + tt];
#pragma unroll 8
            for (int k = 0; k < 64; ++k) acc += xn[half][k] * W[k * 64 + tt];
            ws[OFF_Q1 + (r0 + half) * 64 + tt] = acc;
        } else {
            {
                const float* W  = ws + (half == 0 ? I_WQ : I_WK) + nb_ * 4096;
                const float* bb = ws + (half == 0 ? I_BQ : I_BK) + nb_ * 64;
                float* dst = ws + (half == 0 ? OFF_Q2 : OFF_KB);
                float acc0 = bb[tt], acc1 = acc0;
#pragma unroll 8
                for (int k = 0; k < 64; ++k) {
                    float w = W[k * 64 + tt];
                    acc0 += xn[0][k] * w;
                    acc1 += xn[1][k] * w;
                }
                dst[r0 * 64 + tt]       = acc0;
                dst[(r0 + 1) * 64 + tt] = acc1;
            }
            {
                const float* Wv = ws + I_WV + nb_ * 4096;
                float accv = ws[I_BV + nb_ * 64 + tt];
#pragma unroll 8
                for (int k = 0; k < 64; ++k) accv += xn[half][k] * Wv[k * 64 + tt];
                ws[OFF_VB + (r0 + half) * 64 + tt] = accv;
            }
        }
    }
}

__global__ __launch_bounds__(128) void k_head(float* ws, void* out_raw) {
    __shared__ float xl[64];
    __shared__ float hl[128];
    __shared__ int sflag;
    int r = blockIdx.x, t = threadIdx.x;
    if (t == 0) sflag = ((const int*)(ws + OFF_FLAG))[0];
    if (t < 64) {
        float v = ws[OFF_QVS + r * 64 + t];
        float s = v, ss2 = v * v;
#pragma unroll
        for (int off = 1; off < 64; off <<= 1) { s += __shfl_xor(s, off); ss2 += __shfl_xor(ss2, off); }
        float mu_ = s * (1.f / 64.f);
        float var_ = ss2 * (1.f / 64.f) - mu_ * mu_;
        float rs_ = rsqrtf(fmaxf(var_, 0.f) + 1e-6f);
        xl[t] = (v - mu_) * rs_ * ws[I_FNS + t] + ws[I_FNB + t];
    }
    __syncthreads();
    float acc = ws[I_HB1 + t];
#pragma unroll 8
    for (int k = 0; k < 64; ++k) acc += xl[k] * ws[I_HW1 + k * 128 + t];
    hl[t] = fmaxf(acc, 0.f);
    __syncthreads();
    if (t < 2) {
        float a = ws[I_HB2 + t];
        for (int j = 0; j < 128; ++j) a += hl[j] * ws[I_HW2 + j * 2 + t];
        float v = (t == 0) ? a : __expf(a * 0.5f);
        int idx = (t == 0) ? r : (N2 + r);
        if (sflag) ((bf16*)out_raw)[idx] = __float2bfloat16(v);
        else       ((float*)out_raw)[idx] = v;
    }
}

extern "C" void kernel_launch(void* const* d_in, const int* in_sizes, int n_in,
                              void* d_out, int out_size, void* d_ws, size_t ws_size,
                              hipStream_t stream) {
    float* ws = (float*)d_ws;

    InPtrs ptrs;
    for (int i = 0; i < 32; ++i) ptrs.p[i] = d_in[i];

    void* out = d_out;
    void* args[] = { (void*)&ptrs, (void*)&ws, (void*)&out };
    hipError_t e = hipLaunchCooperativeKernel((const void*)k_mega,
                                              dim3(1024), dim3(256), args, 0, stream);
    if (e != hipSuccess) {
        (void)hipGetLastError();   // clear error state; use fallback sequence
        k_pwf<<<6, 256, 0, stream>>>(ptrs, ws);
        k_cvt<<<dim3(8, 32), 256, 0, stream>>>(ptrs, ws);
        k_emq<<<2048, 256, 0, stream>>>(ws);
        for (int i = 0; i < 6; ++i) {
            k_attn<<<dim3(64, 4, 4), 256, 0, stream>>>(i, ws);
            k_fuse<<<dim3(1024, 2), 128, 0, stream>>>(i, ws);
        }
        k_head<<<2048, 128, 0, stream>>>(ws, d_out);
    }
}

// Round 9
// 1183.862 us; speedup vs baseline: 1.8655x; 1.8655x over previous
//
#include <hip/hip_runtime.h>
#include <hip/hip_bf16.h>

typedef __hip_bfloat16 bf16;
typedef float v2f __attribute__((ext_vector_type(2)));

#define LEN 1024
#define N2 2048            // B * L rows
#define SCALE_L2E 0.5100697918f   // (1/sqrt(8)) * log2(e)

// ---- converted-input float offsets in ws ----
#define I_SCTX   0
#define I_FCTX   4096
#define I_STEST  6144
#define I_OBS    10240
#define I_EW1    10248
#define I_EB1    12040
#define I_EW2    12296
#define I_EB2    28680
#define I_WQ     28744
#define I_BQ     53320
#define I_WK     53704
#define I_BK     78280
#define I_WV     78664
#define I_BV     103240
#define I_WO     103624
#define I_BO     128200
#define I_FW1    128584
#define I_FB1    177736
#define I_FW2    178504
#define I_FB2    227656
#define I_BW1    228040
#define I_BB1    228136
#define I_BW2    228232
#define I_BB2    229000
#define I_NS     229048
#define I_NB     229432
#define I_FNS    229816
#define I_FNB    229880
#define I_HW1    229944
#define I_HB1    238136
#define I_HW2    238264
#define I_HB2    238520

#define OFF_FLAG 240000
#define OFF_PW   240256    // 6 layers x 288 floats: [17][8] (slope,inter)*log2e + 16 sorted bps
#define OFF_QVS  262144
#define OFF_KVS  393216
#define OFF_Q1   524288
#define OFF_Q2   655360
#define OFF_KB   786432
#define OFF_VB   917504
#define OFF_PART 1048576   // partials: [z=4][row=1024][h=8][ks=8][12] floats (row stride 768)

__constant__ int C_OFFS[33] = {
    0, 4096, 6144, 10240, 10248, 12040, 12296, 28680, 28744, 53320, 53704,
    78280, 78664, 103240, 103624, 128200, 128584, 177736, 178504, 227656,
    228040, 228136, 228232, 229000, 229048, 229432, 229816, 229880, 229944,
    238136, 238264, 238520, 238522 };

struct InPtrs { const void* p[32]; };

__device__ __forceinline__ int get_isbf(const void* ns) {
    return (*(const unsigned*)ns == 0x3F803F80u) ? 1 : 0;
}

// ---- merged prologue: input conversion (blocks 0..255) + flag + piecewise
// bias tables (blocks 256..261). pwf reads raw inputs -> no ordering dep.
__global__ __launch_bounds__(256) void k_pre(InPtrs ptrs, float* ws) {
    const int bid = blockIdx.x, t = threadIdx.x;
    const int isbf = get_isbf(ptrs.p[24]);
    if (bid < 256) {
        const int i = bid & 31, sub = bid >> 5;
        const int o0 = C_OFFS[i], n = C_OFFS[i + 1] - o0;
        const void* src = ptrs.p[i];
        for (int j = sub * 256 + t; j < n; j += 8 * 256) {
            float v = isbf ? __bfloat162float(((const bf16*)src)[j])
                           : ((const float*)src)[j];
            ws[o0 + j] = v;
        }
        return;
    }
    // ---- piecewise tables for layer L ----
    const int L = bid - 256;
    __shared__ float w1s[16], b1s[16], bps[16];
    __shared__ int rnk[16];
    auto cv = [&](const void* p, int idx) -> float {
        return isbf ? __bfloat162float(((const bf16*)p)[idx]) : ((const float*)p)[idx];
    };
    if (t == 0 && L == 0) ((int*)(ws + OFF_FLAG))[0] = isbf;
    if (t < 16) {
        float w = cv(ptrs.p[20], L * 16 + t), b0 = cv(ptrs.p[21], L * 16 + t);
        w1s[t] = w; b1s[t] = b0;
        bps[t] = (w != 0.f) ? (-b0 / w) : 1e30f;
    }
    __syncthreads();
    if (t < 16) {
        float me = bps[t]; int r = 0;
        for (int j = 0; j < 16; ++j) {
            float o = bps[j];
            if (o < me || (o == me && j < t)) ++r;
        }
        rnk[t] = r;
    }
    __syncthreads();
    if (t < 16) ws[OFF_PW + L * 288 + 272 + rnk[t]] = bps[t];
    if (t < 136) {
        int s = t >> 3, h = t & 7;
        float slope = 0.f, inter = cv(ptrs.p[23], L * 8 + h);
        for (int j = 0; j < 16; ++j) {
            float w = w1s[j];
            bool act = (w > 0.f) ? (rnk[j] < s)
                     : (w < 0.f) ? (rnk[j] >= s)
                                 : (b1s[j] > 0.f);
            if (act) {
                float w2v = cv(ptrs.p[22], L * 128 + j * 8 + h);
                slope += w * w2v;
                inter += b1s[j] * w2v;
            }
        }
        const float LOG2E = 1.4426950408889634f;
        ws[OFF_PW + L * 288 + (s * 8 + h) * 2]     = slope * LOG2E;
        ws[OFF_PW + L * 288 + (s * 8 + h) * 2 + 1] = inter * LOG2E;
    }
}

// ---- merged embed MLP (ctx + test row r) + layer-0 QKV projections ----
__global__ __launch_bounds__(256) void k_emq(float* ws) {
    __shared__ float hbuf[2][256];
    __shared__ float red[2][256];
    __shared__ float xs[2][64];
    int r = blockIdx.x, t = threadIdx.x;

    float inc[7], int_[7];
    {
        const float* obc = ws + I_OBS + 4;
        const float* obu = ws + I_OBS;
        inc[0] = obc[0]; inc[1] = obc[1]; inc[2] = obc[2]; inc[3] = obc[3];
        int_[0] = obu[0]; int_[1] = obu[1]; int_[2] = obu[2]; int_[3] = obu[3];
        inc[4] = ws[I_SCTX + r * 2]; inc[5] = ws[I_SCTX + r * 2 + 1];
        int_[4] = ws[I_STEST + r * 2]; int_[5] = ws[I_STEST + r * 2 + 1];
        inc[6] = ws[I_FCTX + r]; int_[6] = 0.f;
    }
    float ac = ws[I_EB1 + t], at = ac;
#pragma unroll
    for (int i = 0; i < 7; ++i) {
        float w = ws[I_EW1 + i * 256 + t];
        ac += inc[i] * w; at += int_[i] * w;
    }
    hbuf[0][t] = fmaxf(ac, 0.f);
    hbuf[1][t] = fmaxf(at, 0.f);
    __syncthreads();

    int d = t & 63, p = t >> 6;
    float a0 = 0.f, a1 = 0.f;
#pragma unroll 8
    for (int j = p * 64; j < p * 64 + 64; ++j) {
        float w = ws[I_EW2 + j * 64 + d];
        a0 += hbuf[0][j] * w; a1 += hbuf[1][j] * w;
    }
    red[0][t] = a0; red[1][t] = a1;
    __syncthreads();
    if (t < 128) {
        int which = t >> 6, d2 = t & 63;
        float o = red[which][d2] + red[which][64 + d2] + red[which][128 + d2]
                + red[which][192 + d2] + ws[I_EB2 + d2];
        if (which == 0) { ws[OFF_KVS + r * 64 + d2] = o; xs[1][d2] = o; }
        else            { ws[OFF_QVS + r * 64 + d2] = o; xs[0][d2] = o; }
    }
    __syncthreads();

    int o = t >> 6;
    const float* x = (o == 0) ? xs[0] : xs[1];
    const float* W; const float* bb; float* dst;
    if (o <= 1)      { W = ws + I_WQ; bb = ws + I_BQ; dst = ws + (o == 0 ? OFF_Q1 : OFF_Q2); }
    else if (o == 2) { W = ws + I_WK; bb = ws + I_BK; dst = ws + OFF_KB; }
    else             { W = ws + I_WV; bb = ws + I_BV; dst = ws + OFF_VB; }
    float acc = bb[d];
#pragma unroll 8
    for (int k = 0; k < 64; ++k) acc += x[k] * W[k * 64 + d];
    dst[r * 64 + d] = acc;
}

// ---- attention: 16-key tiles for max occupancy (8 blocks/CU = 32 waves/CU) ----
// grid (qt=64, ks=8, z=4), z = kind*2 + b. Block: q rows [qt*16,+16), keys
// [ks*128, +128) in 8 tiles of 16. LDS 18.4 KB (Ks/Vs 16x68 + bias[16][132] +
// pw; merge overlay aliases all). Thread (h=t&7, qg=(t>>3)&7, ksub=t>>6) owns
// 2 queries, 4 keys/tile, head h. All inner LDS reads broadcast; bias
// precomputed per tile. No online max (scores bounded in log2 domain).
__global__ __launch_bounds__(256, 8) void k_attn(int blk, float* ws) {
    __shared__ float smem[4608];            // 18432 B
    float* Ks  = smem;                      // 16 x 68
    float* Vs  = smem + 1088;               // 16 x 68
    float* bbf = smem + 2176;               // bias [16][132] = 2112
    v2f* pw = (v2f*)(smem + 4288);          // 272 floats

    const int t = threadIdx.x;
    const int qt = blockIdx.x, ks = blockIdx.y, z = blockIdx.z;
    const int b = z & 1, kind = z >> 1;
    const int q0 = qt * 16;
    const float* Qbuf = ws + (kind == 0 ? OFF_Q1 : OFF_Q2);
    const float* Kbuf = ws + OFF_KB;
    const float* Vbuf = ws + OFF_VB;
    const float* sq_src = ws + (kind == 0 ? I_STEST : I_SCTX);
    const float* sk_src = ws + I_SCTX;
    const float* pwg = ws + OFF_PW + blk * 288;   // uniform -> scalar loads

    float bp[16];
#pragma unroll
    for (int j = 0; j < 16; ++j) bp[j] = pwg[272 + j];

    if (t < 136) pw[t] = (v2f){ pwg[t * 2], pwg[t * 2 + 1] };

    const int h    = t & 7;         // head
    const int qg   = (t >> 3) & 7;  // query pair (qg*2, qg*2+1)
    const int ksub = t >> 6;        // key quartet within 16 (== wave id)

    // Q fragments for 2 queries, resident in registers
    v2f qf[2][4];
#pragma unroll
    for (int qq = 0; qq < 2; ++qq) {
        const float* qp = Qbuf + (b * LEN + q0 + qg * 2 + qq) * 64 + h * 8;
        float4 qa = *(const float4*)qp;
        float4 qb = *(const float4*)(qp + 4);
        qf[qq][0] = (v2f){qa.x, qa.y}; qf[qq][1] = (v2f){qa.z, qa.w};
        qf[qq][2] = (v2f){qb.x, qb.y}; qf[qq][3] = (v2f){qb.z, qb.w};
    }
    // query coords for the bias phase (thread computes pair (q=t>>4, k=t&15))
    float sqx, sqy;
    {
        const float* sp = sq_src + (b * LEN + q0 + (t >> 4)) * 2;
        sqx = sp[0]; sqy = sp[1];
    }

    float lsum[2] = {0.f, 0.f};
    v2f oacc[2][4] = {};

    const int kt0 = ks * 8, kt1 = kt0 + 8;   // tiles of 16 keys
    const int kr = t >> 4, jc = (t & 15) * 4;   // staging coords

    // prologue: prefetch tile kt0
    float4 ka, va;
    {
        const float* ksrc = Kbuf + (b * LEN + kt0 * 16 + kr) * 64 + jc;
        const float* vsrc = Vbuf + (b * LEN + kt0 * 16 + kr) * 64 + jc;
        ka = *(const float4*)ksrc;
        va = *(const float4*)vsrc;
    }

    for (int kt = kt0; kt < kt1; ++kt) {
        __syncthreads();               // previous compute done -> LDS writable
        *(float4*)&Ks[kr * 68 + jc] = ka;
        *(float4*)&Vs[kr * 68 + jc] = va;
        {   // bias precompute: 1 (q,k) pair per thread -> bbf[k][q*8 + h0..7]
            int qs = t >> 4, kp = t & 15;
            const float* c0 = sk_src + (b * LEN + kt * 16 + kp) * 2;
            float2 kc0 = *(const float2*)c0;
            float dx0 = sqx - kc0.x, dy0 = sqy - kc0.y;
            float d0 = dx0 * dx0 + dy0 * dy0;
            int s0 = 0;
#pragma unroll
            for (int j = 0; j < 16; ++j) s0 += (d0 > bp[j]);
            const float* p0 = (const float*)(pw + s0 * 8);   // 16 floats: sl,in x8
            float* bd0 = &bbf[kp * 132 + qs * 8];
            float4 a0 = *(const float4*)p0,       a1 = *(const float4*)(p0 + 4);
            float4 a2 = *(const float4*)(p0 + 8), a3 = *(const float4*)(p0 + 12);
            *(float4*)bd0       = make_float4(fmaf(a0.x, d0, a0.y), fmaf(a0.z, d0, a0.w),
                                              fmaf(a1.x, d0, a1.y), fmaf(a1.z, d0, a1.w));
            *(float4*)(bd0 + 4) = make_float4(fmaf(a2.x, d0, a2.y), fmaf(a2.z, d0, a2.w),
                                              fmaf(a3.x, d0, a3.y), fmaf(a3.z, d0, a3.w));
        }
        __syncthreads();

        // prefetch next tile (latency hides under compute below)
        if (kt + 1 < kt1) {
            const float* ksrc = Kbuf + (b * LEN + (kt + 1) * 16 + kr) * 64 + jc;
            const float* vsrc = Vbuf + (b * LEN + (kt + 1) * 16 + kr) * 64 + jc;
            ka = *(const float4*)ksrc;
            va = *(const float4*)vsrc;
        }

        // inner: 4 keys; K/V frags broadcast 8-way, shared across 2 queries
        const float* Kb = &Ks[(ksub * 4) * 68 + h * 8];
        const float* Vb = &Vs[(ksub * 4) * 68 + h * 8];
        const float* Bb = &bbf[(ksub * 4) * 132 + qg * 16 + h];
#pragma unroll
        for (int k4 = 0; k4 < 4; ++k4) {
            const v2f* kf = (const v2f*)(Kb + k4 * 68);
            v2f k0 = kf[0], k1 = kf[1], k2v = kf[2], k3 = kf[3];
            const v2f* vf = (const v2f*)(Vb + k4 * 68);
            v2f v0 = vf[0], v1 = vf[1], v2v = vf[2], v3 = vf[3];
#pragma unroll
            for (int qq = 0; qq < 2; ++qq) {
                float bv = Bb[k4 * 132 + qq * 8];
                v2f a = qf[qq][0] * k0;
                a += qf[qq][1] * k1;
                a += qf[qq][2] * k2v;
                a += qf[qq][3] * k3;
                float sv = fmaf(a.x + a.y, SCALE_L2E, bv);
                float p = exp2f(sv);
                lsum[qq] += p;
                v2f pp = (v2f){p, p};
                oacc[qq][0] += pp * v0;
                oacc[qq][1] += pp * v1;
                oacc[qq][2] += pp * v2v;
                oacc[qq][3] += pp * v3;
            }
        }
    }

    // merge 4 ksub waves via LDS overlay (aliases everything), write partial
    __syncthreads();
    if (ksub) {
#pragma unroll
        for (int qq = 0; qq < 2; ++qq) {
            float* p = &smem[(((ksub - 1) * 16 + qg * 2 + qq) * 8 + h) * 12];
            *(float4*)p       = make_float4(oacc[qq][0].x, oacc[qq][0].y, oacc[qq][1].x, oacc[qq][1].y);
            *(float4*)(p + 4) = make_float4(oacc[qq][2].x, oacc[qq][2].y, oacc[qq][3].x, oacc[qq][3].y);
            p[8] = lsum[qq];
        }
    }
    __syncthreads();
    if (ksub == 0) {
#pragma unroll
        for (int qq = 0; qq < 2; ++qq) {
            int q = qg * 2 + qq;
            float ov[8] = { oacc[qq][0].x, oacc[qq][0].y, oacc[qq][1].x, oacc[qq][1].y,
                            oacc[qq][2].x, oacc[qq][2].y, oacc[qq][3].x, oacc[qq][3].y };
            float lq = lsum[qq];
#pragma unroll
            for (int m = 0; m < 3; ++m) {
                const float* p = &smem[((m * 16 + q) * 8 + h) * 12];
                float4 m0 = *(const float4*)p, m1 = *(const float4*)(p + 4);
                ov[0] += m0.x; ov[1] += m0.y; ov[2] += m0.z; ov[3] += m0.w;
                ov[4] += m1.x; ov[5] += m1.y; ov[6] += m1.z; ov[7] += m1.w;
                lq += p[8];
            }
            float* pp = ws + OFF_PART + (z * LEN + q0 + q) * 768 + (h * 8 + ks) * 12;
            *(float4*)(pp)     = make_float4(ov[0], ov[1], ov[2], ov[3]);
            *(float4*)(pp + 4) = make_float4(ov[4], ov[5], ov[6], ov[7]);
            *(float4*)(pp + 8) = make_float4(lq, 0.f, 0.f, 0.f);
        }
    }
}

// ---- fused: partial-merge + Wo + LN + FFN + LN + next-QKV (+head on last) ----
// 2 rows per 128-thread block. grid (bx=1024, kind=2).
__global__ __launch_bounds__(128) void k_fuse(int blk, float* ws, void* out_raw) {
    __shared__ float raw[1536];       // 2 rows x 768
    __shared__ float xo[2][64];
    __shared__ float xs[2][64];
    __shared__ float hs[2][128];
    __shared__ float xn[2][64];
    const int bx = blockIdx.x, kind = blockIdx.y, t = threadIdx.x;
    const int r0 = bx * 2;            // rows r0, r0+1 (same b: r0 even)
    const int b = r0 >> 10, row0 = r0 & 1023;
    const int z = kind * 2 + b;
    const int half = t >> 6, tt = t & 63;
    float* io = ws + (kind == 0 ? OFF_QVS : OFF_KVS);

    const float* pbase = ws + OFF_PART + (z * LEN + row0) * 768;  // 2 rows contiguous
    for (int i = t; i < 384; i += 128) *(float4*)&raw[i * 4] = *(const float4*)&pbase[i * 4];
    __syncthreads();

    // merge 8 K-split partials per (row=half, h, d): plain sums
    {
        int h = tt >> 3, d = tt & 7;
        const float* rw = raw + half * 768;
        float L = 0.f, o = 0.f;
#pragma unroll
        for (int k2 = 0; k2 < 8; ++k2) {
            L += rw[(h * 8 + k2) * 12 + 8];
            o += rw[(h * 8 + k2) * 12 + d];
        }
        xo[half][tt] = o / L;
    }
    __syncthreads();

    // Wo projection + residual + LN; wave per row
    {
        const float* Wo = ws + I_WO + blk * 4096;
        float acc = ws[I_BO + blk * 64 + tt];
#pragma unroll 8
        for (int j = 0; j < 64; ++j) acc += xo[half][j] * Wo[j * 64 + tt];
        acc += io[(r0 + half) * 64 + tt];
        float s = acc, ss2 = acc * acc;
#pragma unroll
        for (int off = 1; off < 64; off <<= 1) { s += __shfl_xor(s, off); ss2 += __shfl_xor(ss2, off); }
        float mu_ = s * (1.f / 64.f);
        float var_ = ss2 * (1.f / 64.f) - mu_ * mu_;
        float rs_ = rsqrtf(fmaxf(var_, 0.f) + 1e-6f);
        xs[half][tt] = (acc - mu_) * rs_ * ws[I_NS + blk * 64 + tt] + ws[I_NB + blk * 64 + tt];
    }
    __syncthreads();

    // FFN hidden: thread t = column, both rows
    {
        const float* W1 = ws + I_FW1 + blk * 8192;
        float a0 = ws[I_FB1 + blk * 128 + t], a1 = a0;
#pragma unroll 8
        for (int k = 0; k < 64; ++k) {
            float w = W1[k * 128 + t];
            a0 += xs[0][k] * w;
            a1 += xs[1][k] * w;
        }
        hs[0][t] = fmaxf(a0, 0.f);
        hs[1][t] = fmaxf(a1, 0.f);
    }
    __syncthreads();

    // FFN out + residual + LN -> new layer state; wave per row
    {
        const float* W2 = ws + I_FW2 + blk * 8192;
        float a2 = ws[I_FB2 + blk * 64 + tt];
#pragma unroll 8
        for (int k = 0; k < 128; ++k) a2 += hs[half][k] * W2[k * 64 + tt];
        a2 += xs[half][tt];
        float s = a2, ss2 = a2 * a2;
#pragma unroll
        for (int off = 1; off < 64; off <<= 1) { s += __shfl_xor(s, off); ss2 += __shfl_xor(ss2, off); }
        float mu_ = s * (1.f / 64.f);
        float var_ = ss2 * (1.f / 64.f) - mu_ * mu_;
        float rs_ = rsqrtf(fmaxf(var_, 0.f) + 1e-6f);
        float outv = (a2 - mu_) * rs_ * ws[I_NS + blk * 64 + tt] + ws[I_NB + blk * 64 + tt];
        io[(r0 + half) * 64 + tt] = outv;
        xn[half][tt] = outv;
    }
    __syncthreads();

    if (blk < 5) {   // next-layer QKV projection
        const int nb_ = blk + 1;
        if (kind == 0) {
            const float* W = ws + I_WQ + nb_ * 4096;
            float acc = ws[I_BQ + nb_ * 64 + tt];
#pragma unroll 8
            for (int k = 0; k < 64; ++k) acc += xn[half][k] * W[k * 64 + tt];
            ws[OFF_Q1 + (r0 + half) * 64 + tt] = acc;
        } else {
            {
                const float* W  = ws + (half == 0 ? I_WQ : I_WK) + nb_ * 4096;
                const float* bb = ws + (half == 0 ? I_BQ : I_BK) + nb_ * 64;
                float* dst = ws + (half == 0 ? OFF_Q2 : OFF_KB);
                float acc0 = bb[tt], acc1 = acc0;
#pragma unroll 8
                for (int k = 0; k < 64; ++k) {
                    float w = W[k * 64 + tt];
                    acc0 += xn[0][k] * w;
                    acc1 += xn[1][k] * w;
                }
                dst[r0 * 64 + tt]       = acc0;
                dst[(r0 + 1) * 64 + tt] = acc1;
            }
            {
                const float* Wv = ws + I_WV + nb_ * 4096;
                float accv = ws[I_BV + nb_ * 64 + tt];
#pragma unroll 8
                for (int k = 0; k < 64; ++k) accv += xn[half][k] * Wv[k * 64 + tt];
                ws[OFF_VB + (r0 + half) * 64 + tt] = accv;
            }
        }
    } else if (kind == 0) {
        // ---- inline head for rows r0, r0+1 (xn holds final qvs) ----
        if (t == 0) *(int*)&raw[0] = ((const int*)(ws + OFF_FLAG))[0];
        // final LN per row (wave per row), into xo
        {
            float v = xn[half][tt];
            float s = v, ss2 = v * v;
#pragma unroll
            for (int off = 1; off < 64; off <<= 1) { s += __shfl_xor(s, off); ss2 += __shfl_xor(ss2, off); }
            float mu_ = s * (1.f / 64.f);
            float var_ = ss2 * (1.f / 64.f) - mu_ * mu_;
            float rs_ = rsqrtf(fmaxf(var_, 0.f) + 1e-6f);
            xo[half][tt] = (v - mu_) * rs_ * ws[I_FNS + tt] + ws[I_FNB + tt];
        }
        __syncthreads();
        // head hidden: thread t = hidden unit, both rows
        {
            float a0 = ws[I_HB1 + t], a1 = a0;
#pragma unroll 8
            for (int k = 0; k < 64; ++k) {
                float w = ws[I_HW1 + k * 128 + t];
                a0 += xo[0][k] * w;
                a1 += xo[1][k] * w;
            }
            hs[0][t] = fmaxf(a0, 0.f);
            hs[1][t] = fmaxf(a1, 0.f);
        }
        __syncthreads();
        if (t < 4) {
            int row = t >> 1, c = t & 1;
            float a = ws[I_HB2 + c];
            for (int j = 0; j < 128; ++j) a += hs[row][j] * ws[I_HW2 + j * 2 + c];
            float v = (c == 0) ? a : __expf(a * 0.5f);
            int r = r0 + row;
            int idx = (c == 0) ? r : (N2 + r);
            if (*(int*)&raw[0]) ((bf16*)out_raw)[idx] = __float2bfloat16(v);
            else                ((float*)out_raw)[idx] = v;
        }
    }
}

extern "C" void kernel_launch(void* const* d_in, const int* in_sizes, int n_in,
                              void* d_out, int out_size, void* d_ws, size_t ws_size,
                              hipStream_t stream) {
    float* ws = (float*)d_ws;

    InPtrs ptrs;
    for (int i = 0; i < 32; ++i) ptrs.p[i] = d_in[i];

    k_pre<<<262, 256, 0, stream>>>(ptrs, ws);                 // cvt + flag + pw tables
    k_emq<<<2048, 256, 0, stream>>>(ws);                      // embed + layer-0 QKV
    for (int i = 0; i < 6; ++i) {
        k_attn<<<dim3(64, 8, 4), 256, 0, stream>>>(i, ws);
        k_fuse<<<dim3(1024, 2), 128, 0, stream>>>(i, ws, d_out);  // +QKV(i+1); head on i=5
    }
}

// Round 10
// 455.673 us; speedup vs baseline: 4.8467x; 2.5980x over previous
//
#include <hip/hip_runtime.h>
#include <hip/hip_bf16.h>

typedef __hip_bfloat16 bf16;
typedef float v2f __attribute__((ext_vector_type(2)));

#define LEN 1024
#define N2 2048            // B * L rows
#define SCALE_L2E 0.5100697918f   // (1/sqrt(8)) * log2(e)

// ---- converted-input float offsets in ws ----
#define I_SCTX   0
#define I_FCTX   4096
#define I_STEST  6144
#define I_OBS    10240
#define I_EW1    10248
#define I_EB1    12040
#define I_EW2    12296
#define I_EB2    28680
#define I_WQ     28744
#define I_BQ     53320
#define I_WK     53704
#define I_BK     78280
#define I_WV     78664
#define I_BV     103240
#define I_WO     103624
#define I_BO     128200
#define I_FW1    128584
#define I_FB1    177736
#define I_FW2    178504
#define I_FB2    227656
#define I_BW1    228040
#define I_BB1    228136
#define I_BW2    228232
#define I_BB2    229000
#define I_NS     229048
#define I_NB     229432
#define I_FNS    229816
#define I_FNB    229880
#define I_HW1    229944
#define I_HB1    238136
#define I_HW2    238264
#define I_HB2    238520

#define OFF_FLAG 240000
#define OFF_PW   240256    // 6 layers x 288 floats: [17][8] (slope,inter)*log2e + 16 sorted bps
#define OFF_QVS  262144
#define OFF_KVS  393216
#define OFF_Q1   524288
#define OFF_Q2   655360
#define OFF_KB   786432
#define OFF_VB   917504
#define OFF_PART 1048576   // partials: [z=4][row=1024][h=8][ks=8][12] floats (row stride 768)

__constant__ int C_OFFS[33] = {
    0, 4096, 6144, 10240, 10248, 12040, 12296, 28680, 28744, 53320, 53704,
    78280, 78664, 103240, 103624, 128200, 128584, 177736, 178504, 227656,
    228040, 228136, 228232, 229000, 229048, 229432, 229816, 229880, 229944,
    238136, 238264, 238520, 238522 };

struct InPtrs { const void* p[32]; };

__device__ __forceinline__ int get_isbf(const void* ns) {
    return (*(const unsigned*)ns == 0x3F803F80u) ? 1 : 0;
}

// ---- merged prologue: input conversion (blocks 0..255) + flag + piecewise
// bias tables (blocks 256..261). pwf reads raw inputs -> no ordering dep.
__global__ __launch_bounds__(256) void k_pre(InPtrs ptrs, float* ws) {
    const int bid = blockIdx.x, t = threadIdx.x;
    const int isbf = get_isbf(ptrs.p[24]);
    if (bid < 256) {
        const int i = bid & 31, sub = bid >> 5;
        const int o0 = C_OFFS[i], n = C_OFFS[i + 1] - o0;
        const void* src = ptrs.p[i];
        for (int j = sub * 256 + t; j < n; j += 8 * 256) {
            float v = isbf ? __bfloat162float(((const bf16*)src)[j])
                           : ((const float*)src)[j];
            ws[o0 + j] = v;
        }
        return;
    }
    // ---- piecewise tables for layer L ----
    const int L = bid - 256;
    __shared__ float w1s[16], b1s[16], bps[16];
    __shared__ int rnk[16];
    auto cv = [&](const void* p, int idx) -> float {
        return isbf ? __bfloat162float(((const bf16*)p)[idx]) : ((const float*)p)[idx];
    };
    if (t == 0 && L == 0) ((int*)(ws + OFF_FLAG))[0] = isbf;
    if (t < 16) {
        float w = cv(ptrs.p[20], L * 16 + t), b0 = cv(ptrs.p[21], L * 16 + t);
        w1s[t] = w; b1s[t] = b0;
        bps[t] = (w != 0.f) ? (-b0 / w) : 1e30f;
    }
    __syncthreads();
    if (t < 16) {
        float me = bps[t]; int r = 0;
        for (int j = 0; j < 16; ++j) {
            float o = bps[j];
            if (o < me || (o == me && j < t)) ++r;
        }
        rnk[t] = r;
    }
    __syncthreads();
    if (t < 16) ws[OFF_PW + L * 288 + 272 + rnk[t]] = bps[t];
    if (t < 136) {
        int s = t >> 3, h = t & 7;
        float slope = 0.f, inter = cv(ptrs.p[23], L * 8 + h);
        for (int j = 0; j < 16; ++j) {
            float w = w1s[j];
            bool act = (w > 0.f) ? (rnk[j] < s)
                     : (w < 0.f) ? (rnk[j] >= s)
                                 : (b1s[j] > 0.f);
            if (act) {
                float w2v = cv(ptrs.p[22], L * 128 + j * 8 + h);
                slope += w * w2v;
                inter += b1s[j] * w2v;
            }
        }
        const float LOG2E = 1.4426950408889634f;
        ws[OFF_PW + L * 288 + (s * 8 + h) * 2]     = slope * LOG2E;
        ws[OFF_PW + L * 288 + (s * 8 + h) * 2 + 1] = inter * LOG2E;
    }
}

// ---- merged embed MLP (ctx + test row r) + layer-0 QKV projections ----
__global__ __launch_bounds__(256) void k_emq(float* ws) {
    __shared__ float hbuf[2][256];
    __shared__ float red[2][256];
    __shared__ float xs[2][64];
    int r = blockIdx.x, t = threadIdx.x;

    float inc[7], int_[7];
    {
        const float* obc = ws + I_OBS + 4;
        const float* obu = ws + I_OBS;
        inc[0] = obc[0]; inc[1] = obc[1]; inc[2] = obc[2]; inc[3] = obc[3];
        int_[0] = obu[0]; int_[1] = obu[1]; int_[2] = obu[2]; int_[3] = obu[3];
        inc[4] = ws[I_SCTX + r * 2]; inc[5] = ws[I_SCTX + r * 2 + 1];
        int_[4] = ws[I_STEST + r * 2]; int_[5] = ws[I_STEST + r * 2 + 1];
        inc[6] = ws[I_FCTX + r]; int_[6] = 0.f;
    }
    float ac = ws[I_EB1 + t], at = ac;
#pragma unroll
    for (int i = 0; i < 7; ++i) {
        float w = ws[I_EW1 + i * 256 + t];
        ac += inc[i] * w; at += int_[i] * w;
    }
    hbuf[0][t] = fmaxf(ac, 0.f);
    hbuf[1][t] = fmaxf(at, 0.f);
    __syncthreads();

    int d = t & 63, p = t >> 6;
    float a0 = 0.f, a1 = 0.f;
#pragma unroll 8
    for (int j = p * 64; j < p * 64 + 64; ++j) {
        float w = ws[I_EW2 + j * 64 + d];
        a0 += hbuf[0][j] * w; a1 += hbuf[1][j] * w;
    }
    red[0][t] = a0; red[1][t] = a1;
    __syncthreads();
    if (t < 128) {
        int which = t >> 6, d2 = t & 63;
        float o = red[which][d2] + red[which][64 + d2] + red[which][128 + d2]
                + red[which][192 + d2] + ws[I_EB2 + d2];
        if (which == 0) { ws[OFF_KVS + r * 64 + d2] = o; xs[1][d2] = o; }
        else            { ws[OFF_QVS + r * 64 + d2] = o; xs[0][d2] = o; }
    }
    __syncthreads();

    int o = t >> 6;
    const float* x = (o == 0) ? xs[0] : xs[1];
    const float* W; const float* bb; float* dst;
    if (o <= 1)      { W = ws + I_WQ; bb = ws + I_BQ; dst = ws + (o == 0 ? OFF_Q1 : OFF_Q2); }
    else if (o == 2) { W = ws + I_WK; bb = ws + I_BK; dst = ws + OFF_KB; }
    else             { W = ws + I_WV; bb = ws + I_BV; dst = ws + OFF_VB; }
    float acc = bb[d];
#pragma unroll 8
    for (int k = 0; k < 64; ++k) acc += x[k] * W[k * 64 + d];
    dst[r * 64 + d] = acc;
}

// ---- attention: 16-key tiles, 18.4 KB LDS. Launch bounds (256,4): VGPR cap
// 128 so no forced spill; body naturally fits ~64 VGPR -> 8 blocks/CU when it
// does (R9's (256,8) forced VGPR=32 -> 394 MB scratch spill, 184 us).
// grid (qt=64, ks=8, z=4). Thread (h=t&7, qg=(t>>3)&7, ksub=t>>6) owns
// 2 queries, 4 keys/tile, head h. All inner LDS reads broadcast; bias
// precomputed per tile. No online max (scores bounded in log2 domain).
__global__ __launch_bounds__(256, 4) void k_attn(int blk, float* ws) {
    __shared__ float smem[4608];            // 18432 B
    float* Ks  = smem;                      // 16 x 68
    float* Vs  = smem + 1088;               // 16 x 68
    float* bbf = smem + 2176;               // bias [16][132] = 2112
    v2f* pw = (v2f*)(smem + 4288);          // 272 floats

    const int t = threadIdx.x;
    const int qt = blockIdx.x, ks = blockIdx.y, z = blockIdx.z;
    const int b = z & 1, kind = z >> 1;
    const int q0 = qt * 16;
    const float* Qbuf = ws + (kind == 0 ? OFF_Q1 : OFF_Q2);
    const float* Kbuf = ws + OFF_KB;
    const float* Vbuf = ws + OFF_VB;
    const float* sq_src = ws + (kind == 0 ? I_STEST : I_SCTX);
    const float* sk_src = ws + I_SCTX;
    const float* pwg = ws + OFF_PW + blk * 288;   // uniform -> scalar loads

    float bp[16];
#pragma unroll
    for (int j = 0; j < 16; ++j) bp[j] = pwg[272 + j];

    if (t < 136) pw[t] = (v2f){ pwg[t * 2], pwg[t * 2 + 1] };

    const int h    = t & 7;         // head
    const int qg   = (t >> 3) & 7;  // query pair (qg*2, qg*2+1)
    const int ksub = t >> 6;        // key quartet within 16 (== wave id)

    // Q fragments for 2 queries, resident in registers
    v2f qf[2][4];
#pragma unroll
    for (int qq = 0; qq < 2; ++qq) {
        const float* qp = Qbuf + (b * LEN + q0 + qg * 2 + qq) * 64 + h * 8;
        float4 qa = *(const float4*)qp;
        float4 qb = *(const float4*)(qp + 4);
        qf[qq][0] = (v2f){qa.x, qa.y}; qf[qq][1] = (v2f){qa.z, qa.w};
        qf[qq][2] = (v2f){qb.x, qb.y}; qf[qq][3] = (v2f){qb.z, qb.w};
    }
    // query coords for the bias phase (thread computes pair (q=t>>4, k=t&15))
    float sqx, sqy;
    {
        const float* sp = sq_src + (b * LEN + q0 + (t >> 4)) * 2;
        sqx = sp[0]; sqy = sp[1];
    }

    float lsum[2] = {0.f, 0.f};
    v2f oacc[2][4] = {};

    const int kt0 = ks * 8, kt1 = kt0 + 8;   // tiles of 16 keys
    const int kr = t >> 4, jc = (t & 15) * 4;   // staging coords

    // prologue: prefetch tile kt0
    float4 ka, va;
    {
        const float* ksrc = Kbuf + (b * LEN + kt0 * 16 + kr) * 64 + jc;
        const float* vsrc = Vbuf + (b * LEN + kt0 * 16 + kr) * 64 + jc;
        ka = *(const float4*)ksrc;
        va = *(const float4*)vsrc;
    }

    for (int kt = kt0; kt < kt1; ++kt) {
        __syncthreads();               // previous compute done -> LDS writable
        *(float4*)&Ks[kr * 68 + jc] = ka;
        *(float4*)&Vs[kr * 68 + jc] = va;
        {   // bias precompute: 1 (q,k) pair per thread -> bbf[k][q*8 + h0..7]
            int qs = t >> 4, kp = t & 15;
            const float* c0 = sk_src + (b * LEN + kt * 16 + kp) * 2;
            float2 kc0 = *(const float2*)c0;
            float dx0 = sqx - kc0.x, dy0 = sqy - kc0.y;
            float d0 = dx0 * dx0 + dy0 * dy0;
            int s0 = 0;
#pragma unroll
            for (int j = 0; j < 16; ++j) s0 += (d0 > bp[j]);
            const float* p0 = (const float*)(pw + s0 * 8);   // 16 floats: sl,in x8
            float* bd0 = &bbf[kp * 132 + qs * 8];
            float4 a0 = *(const float4*)p0,       a1 = *(const float4*)(p0 + 4);
            float4 a2 = *(const float4*)(p0 + 8), a3 = *(const float4*)(p0 + 12);
            *(float4*)bd0       = make_float4(fmaf(a0.x, d0, a0.y), fmaf(a0.z, d0, a0.w),
                                              fmaf(a1.x, d0, a1.y), fmaf(a1.z, d0, a1.w));
            *(float4*)(bd0 + 4) = make_float4(fmaf(a2.x, d0, a2.y), fmaf(a2.z, d0, a2.w),
                                              fmaf(a3.x, d0, a3.y), fmaf(a3.z, d0, a3.w));
        }
        __syncthreads();

        // prefetch next tile (latency hides under compute below)
        if (kt + 1 < kt1) {
            const float* ksrc = Kbuf + (b * LEN + (kt + 1) * 16 + kr) * 64 + jc;
            const float* vsrc = Vbuf + (b * LEN + (kt + 1) * 16 + kr) * 64 + jc;
            ka = *(const float4*)ksrc;
            va = *(const float4*)vsrc;
        }

        // inner: 4 keys; K/V frags broadcast 8-way, shared across 2 queries
        const float* Kb = &Ks[(ksub * 4) * 68 + h * 8];
        const float* Vb = &Vs[(ksub * 4) * 68 + h * 8];
        const float* Bb = &bbf[(ksub * 4) * 132 + qg * 16 + h];
#pragma unroll
        for (int k4 = 0; k4 < 4; ++k4) {
            const v2f* kf = (const v2f*)(Kb + k4 * 68);
            v2f k0 = kf[0], k1 = kf[1], k2v = kf[2], k3 = kf[3];
            const v2f* vf = (const v2f*)(Vb + k4 * 68);
            v2f v0 = vf[0], v1 = vf[1], v2v = vf[2], v3 = vf[3];
#pragma unroll
            for (int qq = 0; qq < 2; ++qq) {
                float bv = Bb[k4 * 132 + qq * 8];
                v2f a = qf[qq][0] * k0;
                a += qf[qq][1] * k1;
                a += qf[qq][2] * k2v;
                a += qf[qq][3] * k3;
                float sv = fmaf(a.x + a.y, SCALE_L2E, bv);
                float p = exp2f(sv);
                lsum[qq] += p;
                v2f pp = (v2f){p, p};
                oacc[qq][0] += pp * v0;
                oacc[qq][1] += pp * v1;
                oacc[qq][2] += pp * v2v;
                oacc[qq][3] += pp * v3;
            }
        }
    }

    // merge 4 ksub waves via LDS overlay (aliases everything), write partial
    __syncthreads();
    if (ksub) {
#pragma unroll
        for (int qq = 0; qq < 2; ++qq) {
            float* p = &smem[(((ksub - 1) * 16 + qg * 2 + qq) * 8 + h) * 12];
            *(float4*)p       = make_float4(oacc[qq][0].x, oacc[qq][0].y, oacc[qq][1].x, oacc[qq][1].y);
            *(float4*)(p + 4) = make_float4(oacc[qq][2].x, oacc[qq][2].y, oacc[qq][3].x, oacc[qq][3].y);
            p[8] = lsum[qq];
        }
    }
    __syncthreads();
    if (ksub == 0) {
#pragma unroll
        for (int qq = 0; qq < 2; ++qq) {
            int q = qg * 2 + qq;
            float ov[8] = { oacc[qq][0].x, oacc[qq][0].y, oacc[qq][1].x, oacc[qq][1].y,
                            oacc[qq][2].x, oacc[qq][2].y, oacc[qq][3].x, oacc[qq][3].y };
            float lq = lsum[qq];
#pragma unroll
            for (int m = 0; m < 3; ++m) {
                const float* p = &smem[((m * 16 + q) * 8 + h) * 12];
                float4 m0 = *(const float4*)p, m1 = *(const float4*)(p + 4);
                ov[0] += m0.x; ov[1] += m0.y; ov[2] += m0.z; ov[3] += m0.w;
                ov[4] += m1.x; ov[5] += m1.y; ov[6] += m1.z; ov[7] += m1.w;
                lq += p[8];
            }
            float* pp = ws + OFF_PART + (z * LEN + q0 + q) * 768 + (h * 8 + ks) * 12;
            *(float4*)(pp)     = make_float4(ov[0], ov[1], ov[2], ov[3]);
            *(float4*)(pp + 4) = make_float4(ov[4], ov[5], ov[6], ov[7]);
            *(float4*)(pp + 8) = make_float4(lq, 0.f, 0.f, 0.f);
        }
    }
}

// ---- fused: partial-merge + Wo + LN + FFN + LN + next-QKV (+head on last) ----
// 2 rows per 128-thread block. grid (bx=1024, kind=2).
__global__ __launch_bounds__(128) void k_fuse(int blk, float* ws, void* out_raw) {
    __shared__ float raw[1536];       // 2 rows x 768
    __shared__ float xo[2][64];
    __shared__ float xs[2][64];
    __shared__ float hs[2][128];
    __shared__ float xn[2][64];
    const int bx = blockIdx.x, kind = blockIdx.y, t = threadIdx.x;
    const int r0 = bx * 2;            // rows r0, r0+1 (same b: r0 even)
    const int b = r0 >> 10, row0 = r0 & 1023;
    const int z = kind * 2 + b;
    const int half = t >> 6, tt = t & 63;
    float* io = ws + (kind == 0 ? OFF_QVS : OFF_KVS);

    const float* pbase = ws + OFF_PART + (z * LEN + row0) * 768;  // 2 rows contiguous
    for (int i = t; i < 384; i += 128) *(float4*)&raw[i * 4] = *(const float4*)&pbase[i * 4];
    __syncthreads();

    // merge 8 K-split partials per (row=half, h, d): plain sums
    {
        int h = tt >> 3, d = tt & 7;
        const float* rw = raw + half * 768;
        float L = 0.f, o = 0.f;
#pragma unroll
        for (int k2 = 0; k2 < 8; ++k2) {
            L += rw[(h * 8 + k2) * 12 + 8];
            o += rw[(h * 8 + k2) * 12 + d];
        }
        xo[half][tt] = o / L;
    }
    __syncthreads();

    // Wo projection + residual + LN; wave per row
    {
        const float* Wo = ws + I_WO + blk * 4096;
        float acc = ws[I_BO + blk * 64 + tt];
#pragma unroll 8
        for (int j = 0; j < 64; ++j) acc += xo[half][j] * Wo[j * 64 + tt];
        acc += io[(r0 + half) * 64 + tt];
        float s = acc, ss2 = acc * acc;
#pragma unroll
        for (int off = 1; off < 64; off <<= 1) { s += __shfl_xor(s, off); ss2 += __shfl_xor(ss2, off); }
        float mu_ = s * (1.f / 64.f);
        float var_ = ss2 * (1.f / 64.f) - mu_ * mu_;
        float rs_ = rsqrtf(fmaxf(var_, 0.f) + 1e-6f);
        xs[half][tt] = (acc - mu_) * rs_ * ws[I_NS + blk * 64 + tt] + ws[I_NB + blk * 64 + tt];
    }
    __syncthreads();

    // FFN hidden: thread t = column, both rows
    {
        const float* W1 = ws + I_FW1 + blk * 8192;
        float a0 = ws[I_FB1 + blk * 128 + t], a1 = a0;
#pragma unroll 8
        for (int k = 0; k < 64; ++k) {
            float w = W1[k * 128 + t];
            a0 += xs[0][k] * w;
            a1 += xs[1][k] * w;
        }
        hs[0][t] = fmaxf(a0, 0.f);
        hs[1][t] = fmaxf(a1, 0.f);
    }
    __syncthreads();

    // FFN out + residual + LN -> new layer state; wave per row
    {
        const float* W2 = ws + I_FW2 + blk * 8192;
        float a2 = ws[I_FB2 + blk * 64 + tt];
#pragma unroll 8
        for (int k = 0; k < 128; ++k) a2 += hs[half][k] * W2[k * 64 + tt];
        a2 += xs[half][tt];
        float s = a2, ss2 = a2 * a2;
#pragma unroll
        for (int off = 1; off < 64; off <<= 1) { s += __shfl_xor(s, off); ss2 += __shfl_xor(ss2, off); }
        float mu_ = s * (1.f / 64.f);
        float var_ = ss2 * (1.f / 64.f) - mu_ * mu_;
        float rs_ = rsqrtf(fmaxf(var_, 0.f) + 1e-6f);
        float outv = (a2 - mu_) * rs_ * ws[I_NS + blk * 64 + tt] + ws[I_NB + blk * 64 + tt];
        io[(r0 + half) * 64 + tt] = outv;
        xn[half][tt] = outv;
    }
    __syncthreads();

    if (blk < 5) {   // next-layer QKV projection
        const int nb_ = blk + 1;
        if (kind == 0) {
            const float* W = ws + I_WQ + nb_ * 4096;
            float acc = ws[I_BQ + nb_ * 64 + tt];
#pragma unroll 8
            for (int k = 0; k < 64; ++k) acc += xn[half][k] * W[k * 64 + tt];
            ws[OFF_Q1 + (r0 + half) * 64 + tt] = acc;
        } else {
            {
                const float* W  = ws + (half == 0 ? I_WQ : I_WK) + nb_ * 4096;
                const float* bb = ws + (half == 0 ? I_BQ : I_BK) + nb_ * 64;
                float* dst = ws + (half == 0 ? OFF_Q2 : OFF_KB);
                float acc0 = bb[tt], acc1 = acc0;
#pragma unroll 8
                for (int k = 0; k < 64; ++k) {
                    float w = W[k * 64 + tt];
                    acc0 += xn[0][k] * w;
                    acc1 += xn[1][k] * w;
                }
                dst[r0 * 64 + tt]       = acc0;
                dst[(r0 + 1) * 64 + tt] = acc1;
            }
            {
                const float* Wv = ws + I_WV + nb_ * 4096;
                float accv = ws[I_BV + nb_ * 64 + tt];
#pragma unroll 8
                for (int k = 0; k < 64; ++k) accv += xn[half][k] * Wv[k * 64 + tt];
                ws[OFF_VB + (r0 + half) * 64 + tt] = accv;
            }
        }
    } else if (kind == 0) {
        // ---- inline head for rows r0, r0+1 (xn holds final qvs) ----
        if (t == 0) *(int*)&raw[0] = ((const int*)(ws + OFF_FLAG))[0];
        // final LN per row (wave per row), into xo
        {
            float v = xn[half][tt];
            float s = v, ss2 = v * v;
#pragma unroll
            for (int off = 1; off < 64; off <<= 1) { s += __shfl_xor(s, off); ss2 += __shfl_xor(ss2, off); }
            float mu_ = s * (1.f / 64.f);
            float var_ = ss2 * (1.f / 64.f) - mu_ * mu_;
            float rs_ = rsqrtf(fmaxf(var_, 0.f) + 1e-6f);
            xo[half][tt] = (v - mu_) * rs_ * ws[I_FNS + tt] + ws[I_FNB + tt];
        }
        __syncthreads();
        // head hidden: thread t = hidden unit, both rows
        {
            float a0 = ws[I_HB1 + t], a1 = a0;
#pragma unroll 8
            for (int k = 0; k < 64; ++k) {
                float w = ws[I_HW1 + k * 128 + t];
                a0 += xo[0][k] * w;
                a1 += xo[1][k] * w;
            }
            hs[0][t] = fmaxf(a0, 0.f);
            hs[1][t] = fmaxf(a1, 0.f);
        }
        __syncthreads();
        if (t < 4) {
            int row = t >> 1, c = t & 1;
            float a = ws[I_HB2 + c];
            for (int j = 0; j < 128; ++j) a += hs[row][j] * ws[I_HW2 + j * 2 + c];
            float v = (c == 0) ? a : __expf(a * 0.5f);
            int r = r0 + row;
            int idx = (c == 0) ? r : (N2 + r);
            if (*(int*)&raw[0]) ((bf16*)out_raw)[idx] = __float2bfloat16(v);
            else                ((float*)out_raw)[idx] = v;
        }
    }
}

extern "C" void kernel_launch(void* const* d_in, const int* in_sizes, int n_in,
                              void* d_out, int out_size, void* d_ws, size_t ws_size,
                              hipStream_t stream) {
    float* ws = (float*)d_ws;

    InPtrs ptrs;
    for (int i = 0; i < 32; ++i) ptrs.p[i] = d_in[i];

    k_pre<<<262, 256, 0, stream>>>(ptrs, ws);                 // cvt + flag + pw tables
    k_emq<<<2048, 256, 0, stream>>>(ws);                      // embed + layer-0 QKV
    for (int i = 0; i < 6; ++i) {
        k_attn<<<dim3(64, 8, 4), 256, 0, stream>>>(i, ws);
        k_fuse<<<dim3(1024, 2), 128, 0, stream>>>(i, ws, d_out);  // +QKV(i+1); head on i=5
    }
}

// Round 11
// 448.420 us; speedup vs baseline: 4.9251x; 1.0162x over previous
//
#include <hip/hip_runtime.h>
#include <hip/hip_bf16.h>

typedef __hip_bfloat16 bf16;
typedef float v2f __attribute__((ext_vector_type(2)));

#define LEN 1024
#define N2 2048            // B * L rows
#define SCALE_L2E 0.5100697918f   // (1/sqrt(8)) * log2(e)

// ---- converted-input float offsets in ws ----
#define I_SCTX   0
#define I_FCTX   4096
#define I_STEST  6144
#define I_OBS    10240
#define I_EW1    10248
#define I_EB1    12040
#define I_EW2    12296
#define I_EB2    28680
#define I_WQ     28744
#define I_BQ     53320
#define I_WK     53704
#define I_BK     78280
#define I_WV     78664
#define I_BV     103240
#define I_WO     103624
#define I_BO     128200
#define I_FW1    128584
#define I_FB1    177736
#define I_FW2    178504
#define I_FB2    227656
#define I_BW1    228040
#define I_BB1    228136
#define I_BW2    228232
#define I_BB2    229000
#define I_NS     229048
#define I_NB     229432
#define I_FNS    229816
#define I_FNB    229880
#define I_HW1    229944
#define I_HB1    238136
#define I_HW2    238264
#define I_HB2    238520

#define OFF_FLAG 240000
#define OFF_PW   240256    // 6 layers x 288 floats: [17][8] (slope,inter)*log2e + 16 sorted bps
#define OFF_QVS  262144
#define OFF_KVS  393216
#define OFF_Q1   524288
#define OFF_Q2   655360
#define OFF_KB   786432
#define OFF_VB   917504
#define OFF_PART 1048576   // partials: [z=4][row=1024][h=8][ks=8][12] floats (row stride 768)

__constant__ int C_OFFS[33] = {
    0, 4096, 6144, 10240, 10248, 12040, 12296, 28680, 28744, 53320, 53704,
    78280, 78664, 103240, 103624, 128200, 128584, 177736, 178504, 227656,
    228040, 228136, 228232, 229000, 229048, 229432, 229816, 229880, 229944,
    238136, 238264, 238520, 238522 };

struct InPtrs { const void* p[32]; };

__device__ __forceinline__ int get_isbf(const void* ns) {
    return (*(const unsigned*)ns == 0x3F803F80u) ? 1 : 0;
}

// ---- merged prologue: input conversion (blocks 0..255) + flag + piecewise
// bias tables (blocks 256..261). pwf reads raw inputs -> no ordering dep.
__global__ __launch_bounds__(256) void k_pre(InPtrs ptrs, float* ws) {
    const int bid = blockIdx.x, t = threadIdx.x;
    const int isbf = get_isbf(ptrs.p[24]);
    if (bid < 256) {
        const int i = bid & 31, sub = bid >> 5;
        const int o0 = C_OFFS[i], n = C_OFFS[i + 1] - o0;
        const void* src = ptrs.p[i];
        for (int j = sub * 256 + t; j < n; j += 8 * 256) {
            float v = isbf ? __bfloat162float(((const bf16*)src)[j])
                           : ((const float*)src)[j];
            ws[o0 + j] = v;
        }
        return;
    }
    // ---- piecewise tables for layer L ----
    const int L = bid - 256;
    __shared__ float w1s[16], b1s[16], bps[16];
    __shared__ int rnk[16];
    auto cv = [&](const void* p, int idx) -> float {
        return isbf ? __bfloat162float(((const bf16*)p)[idx]) : ((const float*)p)[idx];
    };
    if (t == 0 && L == 0) ((int*)(ws + OFF_FLAG))[0] = isbf;
    if (t < 16) {
        float w = cv(ptrs.p[20], L * 16 + t), b0 = cv(ptrs.p[21], L * 16 + t);
        w1s[t] = w; b1s[t] = b0;
        bps[t] = (w != 0.f) ? (-b0 / w) : 1e30f;
    }
    __syncthreads();
    if (t < 16) {
        float me = bps[t]; int r = 0;
        for (int j = 0; j < 16; ++j) {
            float o = bps[j];
            if (o < me || (o == me && j < t)) ++r;
        }
        rnk[t] = r;
    }
    __syncthreads();
    if (t < 16) ws[OFF_PW + L * 288 + 272 + rnk[t]] = bps[t];
    if (t < 136) {
        int s = t >> 3, h = t & 7;
        float slope = 0.f, inter = cv(ptrs.p[23], L * 8 + h);
        for (int j = 0; j < 16; ++j) {
            float w = w1s[j];
            bool act = (w > 0.f) ? (rnk[j] < s)
                     : (w < 0.f) ? (rnk[j] >= s)
                                 : (b1s[j] > 0.f);
            if (act) {
                float w2v = cv(ptrs.p[22], L * 128 + j * 8 + h);
                slope += w * w2v;
                inter += b1s[j] * w2v;
            }
        }
        const float LOG2E = 1.4426950408889634f;
        ws[OFF_PW + L * 288 + (s * 8 + h) * 2]     = slope * LOG2E;
        ws[OFF_PW + L * 288 + (s * 8 + h) * 2 + 1] = inter * LOG2E;
    }
}

// ---- merged embed MLP (ctx + test row r) + layer-0 QKV projections ----
__global__ __launch_bounds__(256) void k_emq(float* ws) {
    __shared__ float hbuf[2][256];
    __shared__ float red[2][256];
    __shared__ float xs[2][64];
    int r = blockIdx.x, t = threadIdx.x;

    float inc[7], int_[7];
    {
        const float* obc = ws + I_OBS + 4;
        const float* obu = ws + I_OBS;
        inc[0] = obc[0]; inc[1] = obc[1]; inc[2] = obc[2]; inc[3] = obc[3];
        int_[0] = obu[0]; int_[1] = obu[1]; int_[2] = obu[2]; int_[3] = obu[3];
        inc[4] = ws[I_SCTX + r * 2]; inc[5] = ws[I_SCTX + r * 2 + 1];
        int_[4] = ws[I_STEST + r * 2]; int_[5] = ws[I_STEST + r * 2 + 1];
        inc[6] = ws[I_FCTX + r]; int_[6] = 0.f;
    }
    float ac = ws[I_EB1 + t], at = ac;
#pragma unroll
    for (int i = 0; i < 7; ++i) {
        float w = ws[I_EW1 + i * 256 + t];
        ac += inc[i] * w; at += int_[i] * w;
    }
    hbuf[0][t] = fmaxf(ac, 0.f);
    hbuf[1][t] = fmaxf(at, 0.f);
    __syncthreads();

    int d = t & 63, p = t >> 6;
    float a0 = 0.f, a1 = 0.f;
#pragma unroll 8
    for (int j = p * 64; j < p * 64 + 64; ++j) {
        float w = ws[I_EW2 + j * 64 + d];
        a0 += hbuf[0][j] * w; a1 += hbuf[1][j] * w;
    }
    red[0][t] = a0; red[1][t] = a1;
    __syncthreads();
    if (t < 128) {
        int which = t >> 6, d2 = t & 63;
        float o = red[which][d2] + red[which][64 + d2] + red[which][128 + d2]
                + red[which][192 + d2] + ws[I_EB2 + d2];
        if (which == 0) { ws[OFF_KVS + r * 64 + d2] = o; xs[1][d2] = o; }
        else            { ws[OFF_QVS + r * 64 + d2] = o; xs[0][d2] = o; }
    }
    __syncthreads();

    int o = t >> 6;
    const float* x = (o == 0) ? xs[0] : xs[1];
    const float* W; const float* bb; float* dst;
    if (o <= 1)      { W = ws + I_WQ; bb = ws + I_BQ; dst = ws + (o == 0 ? OFF_Q1 : OFF_Q2); }
    else if (o == 2) { W = ws + I_WK; bb = ws + I_BK; dst = ws + OFF_KB; }
    else             { W = ws + I_WV; bb = ws + I_BV; dst = ws + OFF_VB; }
    float acc = bb[d];
#pragma unroll 8
    for (int k = 0; k < 64; ++k) acc += x[k] * W[k * 64 + d];
    dst[r * 64 + d] = acc;
}

// ---- attention: 16-key tiles, 18.4 KB LDS, launch bounds (256,4) (proven:
// forcing 8 waves/EU collapses the allocator to 32 VGPR + 394 MB spill).
// NEW vs R10: the bias-phase kc (s_ctx coords) global load is prefetched one
// tile ahead, like K/V — it was a dependent ~300-cycle stall between the two
// per-tile barriers (load issued after barrier-1, result needed immediately).
// grid (qt=64, ks=8, z=4). Thread (h=t&7, qg=(t>>3)&7, ksub=t>>6) owns
// 2 queries, 4 keys/tile, head h. All inner LDS reads broadcast; bias
// precomputed per tile. No online max (scores bounded in log2 domain).
__global__ __launch_bounds__(256, 4) void k_attn(int blk, float* ws) {
    __shared__ float smem[4608];            // 18432 B
    float* Ks  = smem;                      // 16 x 68
    float* Vs  = smem + 1088;               // 16 x 68
    float* bbf = smem + 2176;               // bias [16][132] = 2112
    v2f* pw = (v2f*)(smem + 4288);          // 272 floats

    const int t = threadIdx.x;
    const int qt = blockIdx.x, ks = blockIdx.y, z = blockIdx.z;
    const int b = z & 1, kind = z >> 1;
    const int q0 = qt * 16;
    const float* Qbuf = ws + (kind == 0 ? OFF_Q1 : OFF_Q2);
    const float* Kbuf = ws + OFF_KB;
    const float* Vbuf = ws + OFF_VB;
    const float* sq_src = ws + (kind == 0 ? I_STEST : I_SCTX);
    const float* sk_src = ws + I_SCTX;
    const float* pwg = ws + OFF_PW + blk * 288;   // uniform -> scalar loads

    float bp[16];
#pragma unroll
    for (int j = 0; j < 16; ++j) bp[j] = pwg[272 + j];

    if (t < 136) pw[t] = (v2f){ pwg[t * 2], pwg[t * 2 + 1] };

    const int h    = t & 7;         // head
    const int qg   = (t >> 3) & 7;  // query pair (qg*2, qg*2+1)
    const int ksub = t >> 6;        // key quartet within 16 (== wave id)

    // Q fragments for 2 queries, resident in registers
    v2f qf[2][4];
#pragma unroll
    for (int qq = 0; qq < 2; ++qq) {
        const float* qp = Qbuf + (b * LEN + q0 + qg * 2 + qq) * 64 + h * 8;
        float4 qa = *(const float4*)qp;
        float4 qb = *(const float4*)(qp + 4);
        qf[qq][0] = (v2f){qa.x, qa.y}; qf[qq][1] = (v2f){qa.z, qa.w};
        qf[qq][2] = (v2f){qb.x, qb.y}; qf[qq][3] = (v2f){qb.z, qb.w};
    }
    // query coords for the bias phase (thread computes pair (q=t>>4, k=t&15))
    float sqx, sqy;
    {
        const float* sp = sq_src + (b * LEN + q0 + (t >> 4)) * 2;
        sqx = sp[0]; sqy = sp[1];
    }

    float lsum[2] = {0.f, 0.f};
    v2f oacc[2][4] = {};

    const int kt0 = ks * 8, kt1 = kt0 + 8;   // tiles of 16 keys
    const int kr = t >> 4, jc = (t & 15) * 4;   // staging coords
    const int kp = t & 15;                      // bias-phase key index

    // prologue: prefetch tile kt0 (K/V fragments AND key coords)
    float4 ka, va;
    float2 kc_pf;
    {
        const float* ksrc = Kbuf + (b * LEN + kt0 * 16 + kr) * 64 + jc;
        const float* vsrc = Vbuf + (b * LEN + kt0 * 16 + kr) * 64 + jc;
        ka = *(const float4*)ksrc;
        va = *(const float4*)vsrc;
        kc_pf = *(const float2*)(sk_src + (b * LEN + kt0 * 16 + kp) * 2);
    }

    for (int kt = kt0; kt < kt1; ++kt) {
        __syncthreads();               // previous compute done -> LDS writable
        *(float4*)&Ks[kr * 68 + jc] = ka;
        *(float4*)&Vs[kr * 68 + jc] = va;
        {   // bias precompute: 1 (q,k) pair per thread -> bbf[k][q*8 + h0..7]
            int qs = t >> 4;
            float dx0 = sqx - kc_pf.x, dy0 = sqy - kc_pf.y;
            float d0 = dx0 * dx0 + dy0 * dy0;
            int s0 = 0;
#pragma unroll
            for (int j = 0; j < 16; ++j) s0 += (d0 > bp[j]);
            const float* p0 = (const float*)(pw + s0 * 8);   // 16 floats: sl,in x8
            float* bd0 = &bbf[kp * 132 + qs * 8];
            float4 a0 = *(const float4*)p0,       a1 = *(const float4*)(p0 + 4);
            float4 a2 = *(const float4*)(p0 + 8), a3 = *(const float4*)(p0 + 12);
            *(float4*)bd0       = make_float4(fmaf(a0.x, d0, a0.y), fmaf(a0.z, d0, a0.w),
                                              fmaf(a1.x, d0, a1.y), fmaf(a1.z, d0, a1.w));
            *(float4*)(bd0 + 4) = make_float4(fmaf(a2.x, d0, a2.y), fmaf(a2.z, d0, a2.w),
                                              fmaf(a3.x, d0, a3.y), fmaf(a3.z, d0, a3.w));
        }
        __syncthreads();

        // prefetch next tile (K/V + kc; latency hides under compute below)
        if (kt + 1 < kt1) {
            const float* ksrc = Kbuf + (b * LEN + (kt + 1) * 16 + kr) * 64 + jc;
            const float* vsrc = Vbuf + (b * LEN + (kt + 1) * 16 + kr) * 64 + jc;
            ka = *(const float4*)ksrc;
            va = *(const float4*)vsrc;
            kc_pf = *(const float2*)(sk_src + (b * LEN + (kt + 1) * 16 + kp) * 2);
        }

        // inner: 4 keys; K/V frags broadcast 8-way, shared across 2 queries
        const float* Kb = &Ks[(ksub * 4) * 68 + h * 8];
        const float* Vb = &Vs[(ksub * 4) * 68 + h * 8];
        const float* Bb = &bbf[(ksub * 4) * 132 + qg * 16 + h];
#pragma unroll
        for (int k4 = 0; k4 < 4; ++k4) {
            const v2f* kf = (const v2f*)(Kb + k4 * 68);
            v2f k0 = kf[0], k1 = kf[1], k2v = kf[2], k3 = kf[3];
            const v2f* vf = (const v2f*)(Vb + k4 * 68);
            v2f v0 = vf[0], v1 = vf[1], v2v = vf[2], v3 = vf[3];
#pragma unroll
            for (int qq = 0; qq < 2; ++qq) {
                float bv = Bb[k4 * 132 + qq * 8];
                v2f a = qf[qq][0] * k0;
                a += qf[qq][1] * k1;
                a += qf[qq][2] * k2v;
                a += qf[qq][3] * k3;
                float sv = fmaf(a.x + a.y, SCALE_L2E, bv);
                float p = exp2f(sv);
                lsum[qq] += p;
                v2f pp = (v2f){p, p};
                oacc[qq][0] += pp * v0;
                oacc[qq][1] += pp * v1;
                oacc[qq][2] += pp * v2v;
                oacc[qq][3] += pp * v3;
            }
        }
    }

    // merge 4 ksub waves via LDS overlay (aliases everything), write partial
    __syncthreads();
    if (ksub) {
#pragma unroll
        for (int qq = 0; qq < 2; ++qq) {
            float* p = &smem[(((ksub - 1) * 16 + qg * 2 + qq) * 8 + h) * 12];
            *(float4*)p       = make_float4(oacc[qq][0].x, oacc[qq][0].y, oacc[qq][1].x, oacc[qq][1].y);
            *(float4*)(p + 4) = make_float4(oacc[qq][2].x, oacc[qq][2].y, oacc[qq][3].x, oacc[qq][3].y);
            p[8] = lsum[qq];
        }
    }
    __syncthreads();
    if (ksub == 0) {
#pragma unroll
        for (int qq = 0; qq < 2; ++qq) {
            int q = qg * 2 + qq;
            float ov[8] = { oacc[qq][0].x, oacc[qq][0].y, oacc[qq][1].x, oacc[qq][1].y,
                            oacc[qq][2].x, oacc[qq][2].y, oacc[qq][3].x, oacc[qq][3].y };
            float lq = lsum[qq];
#pragma unroll
            for (int m = 0; m < 3; ++m) {
                const float* p = &smem[((m * 16 + q) * 8 + h) * 12];
                float4 m0 = *(const float4*)p, m1 = *(const float4*)(p + 4);
                ov[0] += m0.x; ov[1] += m0.y; ov[2] += m0.z; ov[3] += m0.w;
                ov[4] += m1.x; ov[5] += m1.y; ov[6] += m1.z; ov[7] += m1.w;
                lq += p[8];
            }
            float* pp = ws + OFF_PART + (z * LEN + q0 + q) * 768 + (h * 8 + ks) * 12;
            *(float4*)(pp)     = make_float4(ov[0], ov[1], ov[2], ov[3]);
            *(float4*)(pp + 4) = make_float4(ov[4], ov[5], ov[6], ov[7]);
            *(float4*)(pp + 8) = make_float4(lq, 0.f, 0.f, 0.f);
        }
    }
}

// ---- fused: partial-merge + Wo + LN + FFN + LN + next-QKV (+head on last) ----
// 2 rows per 128-thread block. grid (bx=1024, kind=2).
__global__ __launch_bounds__(128) void k_fuse(int blk, float* ws, void* out_raw) {
    __shared__ float raw[1536];       // 2 rows x 768
    __shared__ float xo[2][64];
    __shared__ float xs[2][64];
    __shared__ float hs[2][128];
    __shared__ float xn[2][64];
    const int bx = blockIdx.x, kind = blockIdx.y, t = threadIdx.x;
    const int r0 = bx * 2;            // rows r0, r0+1 (same b: r0 even)
    const int b = r0 >> 10, row0 = r0 & 1023;
    const int z = kind * 2 + b;
    const int half = t >> 6, tt = t & 63;
    float* io = ws + (kind == 0 ? OFF_QVS : OFF_KVS);

    const float* pbase = ws + OFF_PART + (z * LEN + row0) * 768;  // 2 rows contiguous
    for (int i = t; i < 384; i += 128) *(float4*)&raw[i * 4] = *(const float4*)&pbase[i * 4];
    __syncthreads();

    // merge 8 K-split partials per (row=half, h, d): plain sums
    {
        int h = tt >> 3, d = tt & 7;
        const float* rw = raw + half * 768;
        float L = 0.f, o = 0.f;
#pragma unroll
        for (int k2 = 0; k2 < 8; ++k2) {
            L += rw[(h * 8 + k2) * 12 + 8];
            o += rw[(h * 8 + k2) * 12 + d];
        }
        xo[half][tt] = o / L;
    }
    __syncthreads();

    // Wo projection + residual + LN; wave per row
    {
        const float* Wo = ws + I_WO + blk * 4096;
        float acc = ws[I_BO + blk * 64 + tt];
#pragma unroll 8
        for (int j = 0; j < 64; ++j) acc += xo[half][j] * Wo[j * 64 + tt];
        acc += io[(r0 + half) * 64 + tt];
        float s = acc, ss2 = acc * acc;
#pragma unroll
        for (int off = 1; off < 64; off <<= 1) { s += __shfl_xor(s, off); ss2 += __shfl_xor(ss2, off); }
        float mu_ = s * (1.f / 64.f);
        float var_ = ss2 * (1.f / 64.f) - mu_ * mu_;
        float rs_ = rsqrtf(fmaxf(var_, 0.f) + 1e-6f);
        xs[half][tt] = (acc - mu_) * rs_ * ws[I_NS + blk * 64 + tt] + ws[I_NB + blk * 64 + tt];
    }
    __syncthreads();

    // FFN hidden: thread t = column, both rows
    {
        const float* W1 = ws + I_FW1 + blk * 8192;
        float a0 = ws[I_FB1 + blk * 128 + t], a1 = a0;
#pragma unroll 8
        for (int k = 0; k < 64; ++k) {
            float w = W1[k * 128 + t];
            a0 += xs[0][k] * w;
            a1 += xs[1][k] * w;
        }
        hs[0][t] = fmaxf(a0, 0.f);
        hs[1][t] = fmaxf(a1, 0.f);
    }
    __syncthreads();

    // FFN out + residual + LN -> new layer state; wave per row
    {
        const float* W2 = ws + I_FW2 + blk * 8192;
        float a2 = ws[I_FB2 + blk * 64 + tt];
#pragma unroll 8
        for (int k = 0; k < 128; ++k) a2 += hs[half][k] * W2[k * 64 + tt];
        a2 += xs[half][tt];
        float s = a2, ss2 = a2 * a2;
#pragma unroll
        for (int off = 1; off < 64; off <<= 1) { s += __shfl_xor(s, off); ss2 += __shfl_xor(ss2, off); }
        float mu_ = s * (1.f / 64.f);
        float var_ = ss2 * (1.f / 64.f) - mu_ * mu_;
        float rs_ = rsqrtf(fmaxf(var_, 0.f) + 1e-6f);
        float outv = (a2 - mu_) * rs_ * ws[I_NS + blk * 64 + tt] + ws[I_NB + blk * 64 + tt];
        io[(r0 + half) * 64 + tt] = outv;
        xn[half][tt] = outv;
    }
    __syncthreads();

    if (blk < 5) {   // next-layer QKV projection
        const int nb_ = blk + 1;
        if (kind == 0) {
            const float* W = ws + I_WQ + nb_ * 4096;
            float acc = ws[I_BQ + nb_ * 64 + tt];
#pragma unroll 8
            for (int k = 0; k < 64; ++k) acc += xn[half][k] * W[k * 64 + tt];
            ws[OFF_Q1 + (r0 + half) * 64 + tt] = acc;
        } else {
            {
                const float* W  = ws + (half == 0 ? I_WQ : I_WK) + nb_ * 4096;
                const float* bb = ws + (half == 0 ? I_BQ : I_BK) + nb_ * 64;
                float* dst = ws + (half == 0 ? OFF_Q2 : OFF_KB);
                float acc0 = bb[tt], acc1 = acc0;
#pragma unroll 8
                for (int k = 0; k < 64; ++k) {
                    float w = W[k * 64 + tt];
                    acc0 += xn[0][k] * w;
                    acc1 += xn[1][k] * w;
                }
                dst[r0 * 64 + tt]       = acc0;
                dst[(r0 + 1) * 64 + tt] = acc1;
            }
            {
                const float* Wv = ws + I_WV + nb_ * 4096;
                float accv = ws[I_BV + nb_ * 64 + tt];
#pragma unroll 8
                for (int k = 0; k < 64; ++k) accv += xn[half][k] * Wv[k * 64 + tt];
                ws[OFF_VB + (r0 + half) * 64 + tt] = accv;
            }
        }
    } else if (kind == 0) {
        // ---- inline head for rows r0, r0+1 (xn holds final qvs) ----
        if (t == 0) *(int*)&raw[0] = ((const int*)(ws + OFF_FLAG))[0];
        // final LN per row (wave per row), into xo
        {
            float v = xn[half][tt];
            float s = v, ss2 = v * v;
#pragma unroll
            for (int off = 1; off < 64; off <<= 1) { s += __shfl_xor(s, off); ss2 += __shfl_xor(ss2, off); }
            float mu_ = s * (1.f / 64.f);
            float var_ = ss2 * (1.f / 64.f) - mu_ * mu_;
            float rs_ = rsqrtf(fmaxf(var_, 0.f) + 1e-6f);
            xo[half][tt] = (v - mu_) * rs_ * ws[I_FNS + tt] + ws[I_FNB + tt];
        }
        __syncthreads();
        // head hidden: thread t = hidden unit, both rows
        {
            float a0 = ws[I_HB1 + t], a1 = a0;
#pragma unroll 8
            for (int k = 0; k < 64; ++k) {
                float w = ws[I_HW1 + k * 128 + t];
                a0 += xo[0][k] * w;
                a1 += xo[1][k] * w;
            }
            hs[0][t] = fmaxf(a0, 0.f);
            hs[1][t] = fmaxf(a1, 0.f);
        }
        __syncthreads();
        if (t < 4) {
            int row = t >> 1, c = t & 1;
            float a = ws[I_HB2 + c];
            for (int j = 0; j < 128; ++j) a += hs[row][j] * ws[I_HW2 + j * 2 + c];
            float v = (c == 0) ? a : __expf(a * 0.5f);
            int r = r0 + row;
            int idx = (c == 0) ? r : (N2 + r);
            if (*(int*)&raw[0]) ((bf16*)out_raw)[idx] = __float2bfloat16(v);
            else                ((float*)out_raw)[idx] = v;
        }
    }
}

extern "C" void kernel_launch(void* const* d_in, const int* in_sizes, int n_in,
                              void* d_out, int out_size, void* d_ws, size_t ws_size,
                              hipStream_t stream) {
    float* ws = (float*)d_ws;

    InPtrs ptrs;
    for (int i = 0; i < 32; ++i) ptrs.p[i] = d_in[i];

    k_pre<<<262, 256, 0, stream>>>(ptrs, ws);                 // cvt + flag + pw tables
    k_emq<<<2048, 256, 0, stream>>>(ws);                      // embed + layer-0 QKV
    for (int i = 0; i < 6; ++i) {
        k_attn<<<dim3(64, 8, 4), 256, 0, stream>>>(i, ws);
        k_fuse<<<dim3(1024, 2), 128, 0, stream>>>(i, ws, d_out);  // +QKV(i+1); head on i=5
    }
}

// Round 12
// 438.985 us; speedup vs baseline: 5.0310x; 1.0215x over previous
//
#include <hip/hip_runtime.h>
#include <hip/hip_bf16.h>

typedef __hip_bfloat16 bf16;
typedef float v2f __attribute__((ext_vector_type(2)));

#define LEN 1024
#define N2 2048            // B * L rows
#define SCALE_L2E 0.5100697918f   // (1/sqrt(8)) * log2(e)

// ---- converted-input float offsets in ws ----
#define I_SCTX   0
#define I_FCTX   4096
#define I_STEST  6144
#define I_OBS    10240
#define I_EW1    10248
#define I_EB1    12040
#define I_EW2    12296
#define I_EB2    28680
#define I_WQ     28744
#define I_BQ     53320
#define I_WK     53704
#define I_BK     78280
#define I_WV     78664
#define I_BV     103240
#define I_WO     103624
#define I_BO     128200
#define I_FW1    128584
#define I_FB1    177736
#define I_FW2    178504
#define I_FB2    227656
#define I_BW1    228040
#define I_BB1    228136
#define I_BW2    228232
#define I_BB2    229000
#define I_NS     229048
#define I_NB     229432
#define I_FNS    229816
#define I_FNB    229880
#define I_HW1    229944
#define I_HB1    238136
#define I_HW2    238264
#define I_HB2    238520

#define OFF_FLAG 240000
#define OFF_PW   240256    // 6 layers x 288 floats: [17][8] (slope,inter)*log2e + 16 sorted bps
#define OFF_QVS  262144
#define OFF_KVS  393216
#define OFF_Q1   524288
#define OFF_Q2   655360
#define OFF_KB   786432
#define OFF_VB   917504
#define OFF_PART 1048576   // partials: [z=4][row=1024][h=8][ks=8][12] floats (row stride 768)

__constant__ int C_OFFS[33] = {
    0, 4096, 6144, 10240, 10248, 12040, 12296, 28680, 28744, 53320, 53704,
    78280, 78664, 103240, 103624, 128200, 128584, 177736, 178504, 227656,
    228040, 228136, 228232, 229000, 229048, 229432, 229816, 229880, 229944,
    238136, 238264, 238520, 238522 };

struct InPtrs { const void* p[32]; };

__device__ __forceinline__ int get_isbf(const void* ns) {
    return (*(const unsigned*)ns == 0x3F803F80u) ? 1 : 0;
}

// ---- merged prologue: input conversion (blocks 0..255) + flag + piecewise
// bias tables (blocks 256..261). pwf reads raw inputs -> no ordering dep.
__global__ __launch_bounds__(256) void k_pre(InPtrs ptrs, float* ws) {
    const int bid = blockIdx.x, t = threadIdx.x;
    const int isbf = get_isbf(ptrs.p[24]);
    if (bid < 256) {
        const int i = bid & 31, sub = bid >> 5;
        const int o0 = C_OFFS[i], n = C_OFFS[i + 1] - o0;
        const void* src = ptrs.p[i];
        for (int j = sub * 256 + t; j < n; j += 8 * 256) {
            float v = isbf ? __bfloat162float(((const bf16*)src)[j])
                           : ((const float*)src)[j];
            ws[o0 + j] = v;
        }
        return;
    }
    // ---- piecewise tables for layer L ----
    const int L = bid - 256;
    __shared__ float w1s[16], b1s[16], bps[16];
    __shared__ int rnk[16];
    auto cv = [&](const void* p, int idx) -> float {
        return isbf ? __bfloat162float(((const bf16*)p)[idx]) : ((const float*)p)[idx];
    };
    if (t == 0 && L == 0) ((int*)(ws + OFF_FLAG))[0] = isbf;
    if (t < 16) {
        float w = cv(ptrs.p[20], L * 16 + t), b0 = cv(ptrs.p[21], L * 16 + t);
        w1s[t] = w; b1s[t] = b0;
        bps[t] = (w != 0.f) ? (-b0 / w) : 1e30f;
    }
    __syncthreads();
    if (t < 16) {
        float me = bps[t]; int r = 0;
        for (int j = 0; j < 16; ++j) {
            float o = bps[j];
            if (o < me || (o == me && j < t)) ++r;
        }
        rnk[t] = r;
    }
    __syncthreads();
    if (t < 16) ws[OFF_PW + L * 288 + 272 + rnk[t]] = bps[t];
    if (t < 136) {
        int s = t >> 3, h = t & 7;
        float slope = 0.f, inter = cv(ptrs.p[23], L * 8 + h);
        for (int j = 0; j < 16; ++j) {
            float w = w1s[j];
            bool act = (w > 0.f) ? (rnk[j] < s)
                     : (w < 0.f) ? (rnk[j] >= s)
                                 : (b1s[j] > 0.f);
            if (act) {
                float w2v = cv(ptrs.p[22], L * 128 + j * 8 + h);
                slope += w * w2v;
                inter += b1s[j] * w2v;
            }
        }
        const float LOG2E = 1.4426950408889634f;
        ws[OFF_PW + L * 288 + (s * 8 + h) * 2]     = slope * LOG2E;
        ws[OFF_PW + L * 288 + (s * 8 + h) * 2 + 1] = inter * LOG2E;
    }
}

// ---- merged embed MLP (ctx + test row r) + layer-0 QKV projections ----
__global__ __launch_bounds__(256) void k_emq(float* ws) {
    __shared__ float hbuf[2][256];
    __shared__ float red[2][256];
    __shared__ float xs[2][64];
    int r = blockIdx.x, t = threadIdx.x;

    float inc[7], int_[7];
    {
        const float* obc = ws + I_OBS + 4;
        const float* obu = ws + I_OBS;
        inc[0] = obc[0]; inc[1] = obc[1]; inc[2] = obc[2]; inc[3] = obc[3];
        int_[0] = obu[0]; int_[1] = obu[1]; int_[2] = obu[2]; int_[3] = obu[3];
        inc[4] = ws[I_SCTX + r * 2]; inc[5] = ws[I_SCTX + r * 2 + 1];
        int_[4] = ws[I_STEST + r * 2]; int_[5] = ws[I_STEST + r * 2 + 1];
        inc[6] = ws[I_FCTX + r]; int_[6] = 0.f;
    }
    float ac = ws[I_EB1 + t], at = ac;
#pragma unroll
    for (int i = 0; i < 7; ++i) {
        float w = ws[I_EW1 + i * 256 + t];
        ac += inc[i] * w; at += int_[i] * w;
    }
    hbuf[0][t] = fmaxf(ac, 0.f);
    hbuf[1][t] = fmaxf(at, 0.f);
    __syncthreads();

    int d = t & 63, p = t >> 6;
    float a0 = 0.f, a1 = 0.f;
#pragma unroll 8
    for (int j = p * 64; j < p * 64 + 64; ++j) {
        float w = ws[I_EW2 + j * 64 + d];
        a0 += hbuf[0][j] * w; a1 += hbuf[1][j] * w;
    }
    red[0][t] = a0; red[1][t] = a1;
    __syncthreads();
    if (t < 128) {
        int which = t >> 6, d2 = t & 63;
        float o = red[which][d2] + red[which][64 + d2] + red[which][128 + d2]
                + red[which][192 + d2] + ws[I_EB2 + d2];
        if (which == 0) { ws[OFF_KVS + r * 64 + d2] = o; xs[1][d2] = o; }
        else            { ws[OFF_QVS + r * 64 + d2] = o; xs[0][d2] = o; }
    }
    __syncthreads();

    int o = t >> 6;
    const float* x = (o == 0) ? xs[0] : xs[1];
    const float* W; const float* bb; float* dst;
    if (o <= 1)      { W = ws + I_WQ; bb = ws + I_BQ; dst = ws + (o == 0 ? OFF_Q1 : OFF_Q2); }
    else if (o == 2) { W = ws + I_WK; bb = ws + I_BK; dst = ws + OFF_KB; }
    else             { W = ws + I_WV; bb = ws + I_BV; dst = ws + OFF_VB; }
    float acc = bb[d];
#pragma unroll 8
    for (int k = 0; k < 64; ++k) acc += x[k] * W[k * 64 + d];
    dst[r * 64 + d] = acc;
}

// ---- attention: wave-private tiles, NO per-tile barriers ----
// Each wave w (= ksub) owns key rows [4w, 4w+4) of every 16-key tile: it
// stages its own K/V rows (kr = t>>4 lands in-wave), computes the bias rows
// for ITS keys x all 16 queries (k = 4w + (t&3), q = (t>>2)&15: 64 pairs =
// 64 lanes), and the inner loop reads only its own rows. Zero cross-wave
// LDS traffic inside the kt loop -> both per-tile barriers deleted (16/block
// -> 3: one after pw staging, two at the final merge). Within-wave LDS
// write->read ordering is compiler-handled (lgkmcnt); tile kt+1's LDS writes
// follow tile kt's reads in program order, so no double-buffer needed.
// grid (qt=64, ks=8, z=4); launch bounds (256,4) (proven: forcing 8 waves/EU
// collapses the allocator to 32 VGPR + 394 MB spill).
__global__ __launch_bounds__(256, 4) void k_attn(int blk, float* ws) {
    __shared__ float smem[4608];            // 18432 B
    float* Ks  = smem;                      // 16 x 68
    float* Vs  = smem + 1088;               // 16 x 68
    float* bbf = smem + 2176;               // bias [16][132] = 2112
    v2f* pw = (v2f*)(smem + 4288);          // 272 floats

    const int t = threadIdx.x;
    const int qt = blockIdx.x, ks = blockIdx.y, z = blockIdx.z;
    const int b = z & 1, kind = z >> 1;
    const int q0 = qt * 16;
    const float* Qbuf = ws + (kind == 0 ? OFF_Q1 : OFF_Q2);
    const float* Kbuf = ws + OFF_KB;
    const float* Vbuf = ws + OFF_VB;
    const float* sq_src = ws + (kind == 0 ? I_STEST : I_SCTX);
    const float* sk_src = ws + I_SCTX;
    const float* pwg = ws + OFF_PW + blk * 288;   // uniform -> scalar loads

    float bp[16];
#pragma unroll
    for (int j = 0; j < 16; ++j) bp[j] = pwg[272 + j];

    if (t < 136) pw[t] = (v2f){ pwg[t * 2], pwg[t * 2 + 1] };

    const int h    = t & 7;         // head (inner loop)
    const int qg   = (t >> 3) & 7;  // query pair (qg*2, qg*2+1) (inner loop)
    const int ksub = t >> 6;        // wave id == key quartet [4*ksub, +4)

    // Q fragments for 2 queries, resident in registers
    v2f qf[2][4];
#pragma unroll
    for (int qq = 0; qq < 2; ++qq) {
        const float* qp = Qbuf + (b * LEN + q0 + qg * 2 + qq) * 64 + h * 8;
        float4 qa = *(const float4*)qp;
        float4 qb = *(const float4*)(qp + 4);
        qf[qq][0] = (v2f){qa.x, qa.y}; qf[qq][1] = (v2f){qa.z, qa.w};
        qf[qq][2] = (v2f){qb.x, qb.y}; qf[qq][3] = (v2f){qb.z, qb.w};
    }
    // bias-phase coords: this thread handles (k = 4*ksub + (t&3), q = (t>>2)&15)
    const int kp = ksub * 4 + (t & 3);      // key row (wave-private quartet)
    const int qs = (t >> 2) & 15;           // query for bias
    float sqx, sqy;
    {
        const float* sp = sq_src + (b * LEN + q0 + qs) * 2;
        sqx = sp[0]; sqy = sp[1];
    }

    float lsum[2] = {0.f, 0.f};
    v2f oacc[2][4] = {};

    const int kt0 = ks * 8, kt1 = kt0 + 8;   // tiles of 16 keys
    const int kr = t >> 4, jc = (t & 15) * 4;   // staging coords (kr in-wave)

    // prologue: prefetch tile kt0 (K/V fragments AND key coords)
    float4 ka, va;
    float2 kc_pf;
    {
        const float* ksrc = Kbuf + (b * LEN + kt0 * 16 + kr) * 64 + jc;
        const float* vsrc = Vbuf + (b * LEN + kt0 * 16 + kr) * 64 + jc;
        ka = *(const float4*)ksrc;
        va = *(const float4*)vsrc;
        kc_pf = *(const float2*)(sk_src + (b * LEN + kt0 * 16 + kp) * 2);
    }

    __syncthreads();                  // pw table visible to all waves

    for (int kt = kt0; kt < kt1; ++kt) {
        // stage this wave's K/V rows (within-wave write->read only)
        *(float4*)&Ks[kr * 68 + jc] = ka;
        *(float4*)&Vs[kr * 68 + jc] = va;
        {   // bias precompute for wave-private keys: (kp, qs) pair
            float dx0 = sqx - kc_pf.x, dy0 = sqy - kc_pf.y;
            float d0 = dx0 * dx0 + dy0 * dy0;
            int s0 = 0;
#pragma unroll
            for (int j = 0; j < 16; ++j) s0 += (d0 > bp[j]);
            const float* p0 = (const float*)(pw + s0 * 8);   // 16 floats: sl,in x8
            float* bd0 = &bbf[kp * 132 + qs * 8];
            float4 a0 = *(const float4*)p0,       a1 = *(const float4*)(p0 + 4);
            float4 a2 = *(const float4*)(p0 + 8), a3 = *(const float4*)(p0 + 12);
            *(float4*)bd0       = make_float4(fmaf(a0.x, d0, a0.y), fmaf(a0.z, d0, a0.w),
                                              fmaf(a1.x, d0, a1.y), fmaf(a1.z, d0, a1.w));
            *(float4*)(bd0 + 4) = make_float4(fmaf(a2.x, d0, a2.y), fmaf(a2.z, d0, a2.w),
                                              fmaf(a3.x, d0, a3.y), fmaf(a3.z, d0, a3.w));
        }

        // prefetch next tile (K/V + kc; latency hides under compute below)
        if (kt + 1 < kt1) {
            const float* ksrc = Kbuf + (b * LEN + (kt + 1) * 16 + kr) * 64 + jc;
            const float* vsrc = Vbuf + (b * LEN + (kt + 1) * 16 + kr) * 64 + jc;
            ka = *(const float4*)ksrc;
            va = *(const float4*)vsrc;
            kc_pf = *(const float2*)(sk_src + (b * LEN + (kt + 1) * 16 + kp) * 2);
        }

        // inner: 4 wave-private keys; K/V frags broadcast 8-way, 2 queries each
        const float* Kb = &Ks[(ksub * 4) * 68 + h * 8];
        const float* Vb = &Vs[(ksub * 4) * 68 + h * 8];
        const float* Bb = &bbf[(ksub * 4) * 132 + qg * 16 + h];
#pragma unroll
        for (int k4 = 0; k4 < 4; ++k4) {
            const v2f* kf = (const v2f*)(Kb + k4 * 68);
            v2f k0 = kf[0], k1 = kf[1], k2v = kf[2], k3 = kf[3];
            const v2f* vf = (const v2f*)(Vb + k4 * 68);
            v2f v0 = vf[0], v1 = vf[1], v2v = vf[2], v3 = vf[3];
#pragma unroll
            for (int qq = 0; qq < 2; ++qq) {
                float bv = Bb[k4 * 132 + qq * 8];
                v2f a = qf[qq][0] * k0;
                a += qf[qq][1] * k1;
                a += qf[qq][2] * k2v;
                a += qf[qq][3] * k3;
                float sv = fmaf(a.x + a.y, SCALE_L2E, bv);
                float p = exp2f(sv);
                lsum[qq] += p;
                v2f pp = (v2f){p, p};
                oacc[qq][0] += pp * v0;
                oacc[qq][1] += pp * v1;
                oacc[qq][2] += pp * v2v;
                oacc[qq][3] += pp * v3;
            }
        }
    }

    // merge 4 ksub waves via LDS overlay (aliases everything), write partial
    __syncthreads();
    if (ksub) {
#pragma unroll
        for (int qq = 0; qq < 2; ++qq) {
            float* p = &smem[(((ksub - 1) * 16 + qg * 2 + qq) * 8 + h) * 12];
            *(float4*)p       = make_float4(oacc[qq][0].x, oacc[qq][0].y, oacc[qq][1].x, oacc[qq][1].y);
            *(float4*)(p + 4) = make_float4(oacc[qq][2].x, oacc[qq][2].y, oacc[qq][3].x, oacc[qq][3].y);
            p[8] = lsum[qq];
        }
    }
    __syncthreads();
    if (ksub == 0) {
#pragma unroll
        for (int qq = 0; qq < 2; ++qq) {
            int q = qg * 2 + qq;
            float ov[8] = { oacc[qq][0].x, oacc[qq][0].y, oacc[qq][1].x, oacc[qq][1].y,
                            oacc[qq][2].x, oacc[qq][2].y, oacc[qq][3].x, oacc[qq][3].y };
            float lq = lsum[qq];
#pragma unroll
            for (int m = 0; m < 3; ++m) {
                const float* p = &smem[((m * 16 + q) * 8 + h) * 12];
                float4 m0 = *(const float4*)p, m1 = *(const float4*)(p + 4);
                ov[0] += m0.x; ov[1] += m0.y; ov[2] += m0.z; ov[3] += m0.w;
                ov[4] += m1.x; ov[5] += m1.y; ov[6] += m1.z; ov[7] += m1.w;
                lq += p[8];
            }
            float* pp = ws + OFF_PART + (z * LEN + q0 + q) * 768 + (h * 8 + ks) * 12;
            *(float4*)(pp)     = make_float4(ov[0], ov[1], ov[2], ov[3]);
            *(float4*)(pp + 4) = make_float4(ov[4], ov[5], ov[6], ov[7]);
            *(float4*)(pp + 8) = make_float4(lq, 0.f, 0.f, 0.f);
        }
    }
}

// ---- fused: partial-merge + Wo + LN + FFN + LN + next-QKV (+head on last) ----
// 2 rows per 128-thread block. grid (bx=1024, kind=2).
__global__ __launch_bounds__(128) void k_fuse(int blk, float* ws, void* out_raw) {
    __shared__ float raw[1536];       // 2 rows x 768
    __shared__ float xo[2][64];
    __shared__ float xs[2][64];
    __shared__ float hs[2][128];
    __shared__ float xn[2][64];
    const int bx = blockIdx.x, kind = blockIdx.y, t = threadIdx.x;
    const int r0 = bx * 2;            // rows r0, r0+1 (same b: r0 even)
    const int b = r0 >> 10, row0 = r0 & 1023;
    const int z = kind * 2 + b;
    const int half = t >> 6, tt = t & 63;
    float* io = ws + (kind == 0 ? OFF_QVS : OFF_KVS);

    const float* pbase = ws + OFF_PART + (z * LEN + row0) * 768;  // 2 rows contiguous
    for (int i = t; i < 384; i += 128) *(float4*)&raw[i * 4] = *(const float4*)&pbase[i * 4];
    __syncthreads();

    // merge 8 K-split partials per (row=half, h, d): plain sums
    {
        int h = tt >> 3, d = tt & 7;
        const float* rw = raw + half * 768;
        float L = 0.f, o = 0.f;
#pragma unroll
        for (int k2 = 0; k2 < 8; ++k2) {
            L += rw[(h * 8 + k2) * 12 + 8];
            o += rw[(h * 8 + k2) * 12 + d];
        }
        xo[half][tt] = o / L;
    }
    __syncthreads();

    // Wo projection + residual + LN; wave per row
    {
        const float* Wo = ws + I_WO + blk * 4096;
        float acc = ws[I_BO + blk * 64 + tt];
#pragma unroll 8
        for (int j = 0; j < 64; ++j) acc += xo[half][j] * Wo[j * 64 + tt];
        acc += io[(r0 + half) * 64 + tt];
        float s = acc, ss2 = acc * acc;
#pragma unroll
        for (int off = 1; off < 64; off <<= 1) { s += __shfl_xor(s, off); ss2 += __shfl_xor(ss2, off); }
        float mu_ = s * (1.f / 64.f);
        float var_ = ss2 * (1.f / 64.f) - mu_ * mu_;
        float rs_ = rsqrtf(fmaxf(var_, 0.f) + 1e-6f);
        xs[half][tt] = (acc - mu_) * rs_ * ws[I_NS + blk * 64 + tt] + ws[I_NB + blk * 64 + tt];
    }
    __syncthreads();

    // FFN hidden: thread t = column, both rows
    {
        const float* W1 = ws + I_FW1 + blk * 8192;
        float a0 = ws[I_FB1 + blk * 128 + t], a1 = a0;
#pragma unroll 8
        for (int k = 0; k < 64; ++k) {
            float w = W1[k * 128 + t];
            a0 += xs[0][k] * w;
            a1 += xs[1][k] * w;
        }
        hs[0][t] = fmaxf(a0, 0.f);
        hs[1][t] = fmaxf(a1, 0.f);
    }
    __syncthreads();

    // FFN out + residual + LN -> new layer state; wave per row
    {
        const float* W2 = ws + I_FW2 + blk * 8192;
        float a2 = ws[I_FB2 + blk * 64 + tt];
#pragma unroll 8
        for (int k = 0; k < 128; ++k) a2 += hs[half][k] * W2[k * 64 + tt];
        a2 += xs[half][tt];
        float s = a2, ss2 = a2 * a2;
#pragma unroll
        for (int off = 1; off < 64; off <<= 1) { s += __shfl_xor(s, off); ss2 += __shfl_xor(ss2, off); }
        float mu_ = s * (1.f / 64.f);
        float var_ = ss2 * (1.f / 64.f) - mu_ * mu_;
        float rs_ = rsqrtf(fmaxf(var_, 0.f) + 1e-6f);
        float outv = (a2 - mu_) * rs_ * ws[I_NS + blk * 64 + tt] + ws[I_NB + blk * 64 + tt];
        io[(r0 + half) * 64 + tt] = outv;
        xn[half][tt] = outv;
    }
    __syncthreads();

    if (blk < 5) {   // next-layer QKV projection
        const int nb_ = blk + 1;
        if (kind == 0) {
            const float* W = ws + I_WQ + nb_ * 4096;
            float acc = ws[I_BQ + nb_ * 64 + tt];
#pragma unroll 8
            for (int k = 0; k < 64; ++k) acc += xn[half][k] * W[k * 64 + tt];
            ws[OFF_Q1 + (r0 + half) * 64 + tt] = acc;
        } else {
            {
                const float* W  = ws + (half == 0 ? I_WQ : I_WK) + nb_ * 4096;
                const float* bb = ws + (half == 0 ? I_BQ : I_BK) + nb_ * 64;
                float* dst = ws + (half == 0 ? OFF_Q2 : OFF_KB);
                float acc0 = bb[tt], acc1 = acc0;
#pragma unroll 8
                for (int k = 0; k < 64; ++k) {
                    float w = W[k * 64 + tt];
                    acc0 += xn[0][k] * w;
                    acc1 += xn[1][k] * w;
                }
                dst[r0 * 64 + tt]       = acc0;
                dst[(r0 + 1) * 64 + tt] = acc1;
            }
            {
                const float* Wv = ws + I_WV + nb_ * 4096;
                float accv = ws[I_BV + nb_ * 64 + tt];
#pragma unroll 8
                for (int k = 0; k < 64; ++k) accv += xn[half][k] * Wv[k * 64 + tt];
                ws[OFF_VB + (r0 + half) * 64 + tt] = accv;
            }
        }
    } else if (kind == 0) {
        // ---- inline head for rows r0, r0+1 (xn holds final qvs) ----
        if (t == 0) *(int*)&raw[0] = ((const int*)(ws + OFF_FLAG))[0];
        // final LN per row (wave per row), into xo
        {
            float v = xn[half][tt];
            float s = v, ss2 = v * v;
#pragma unroll
            for (int off = 1; off < 64; off <<= 1) { s += __shfl_xor(s, off); ss2 += __shfl_xor(ss2, off); }
            float mu_ = s * (1.f / 64.f);
            float var_ = ss2 * (1.f / 64.f) - mu_ * mu_;
            float rs_ = rsqrtf(fmaxf(var_, 0.f) + 1e-6f);
            xo[half][tt] = (v - mu_) * rs_ * ws[I_FNS + tt] + ws[I_FNB + tt];
        }
        __syncthreads();
        // head hidden: thread t = hidden unit, both rows
        {
            float a0 = ws[I_HB1 + t], a1 = a0;
#pragma unroll 8
            for (int k = 0; k < 64; ++k) {
                float w = ws[I_HW1 + k * 128 + t];
                a0 += xo[0][k] * w;
                a1 += xo[1][k] * w;
            }
            hs[0][t] = fmaxf(a0, 0.f);
            hs[1][t] = fmaxf(a1, 0.f);
        }
        __syncthreads();
        if (t < 4) {
            int row = t >> 1, c = t & 1;
            float a = ws[I_HB2 + c];
            for (int j = 0; j < 128; ++j) a += hs[row][j] * ws[I_HW2 + j * 2 + c];
            float v = (c == 0) ? a : __expf(a * 0.5f);
            int r = r0 + row;
            int idx = (c == 0) ? r : (N2 + r);
            if (*(int*)&raw[0]) ((bf16*)out_raw)[idx] = __float2bfloat16(v);
            else                ((float*)out_raw)[idx] = v;
        }
    }
}

extern "C" void kernel_launch(void* const* d_in, const int* in_sizes, int n_in,
                              void* d_out, int out_size, void* d_ws, size_t ws_size,
                              hipStream_t stream) {
    float* ws = (float*)d_ws;

    InPtrs ptrs;
    for (int i = 0; i < 32; ++i) ptrs.p[i] = d_in[i];

    k_pre<<<262, 256, 0, stream>>>(ptrs, ws);                 // cvt + flag + pw tables
    k_emq<<<2048, 256, 0, stream>>>(ws);                      // embed + layer-0 QKV
    for (int i = 0; i < 6; ++i) {
        k_attn<<<dim3(64, 8, 4), 256, 0, stream>>>(i, ws);
        k_fuse<<<dim3(1024, 2), 128, 0, stream>>>(i, ws, d_out);  // +QKV(i+1); head on i=5
    }
}

// Round 13
// 435.110 us; speedup vs baseline: 5.0758x; 1.0089x over previous
//
#include <hip/hip_runtime.h>
#include <hip/hip_bf16.h>

typedef __hip_bfloat16 bf16;
typedef float v2f __attribute__((ext_vector_type(2)));

#define LEN 1024
#define N2 2048            // B * L rows
#define SCALE_L2E 0.5100697918f   // (1/sqrt(8)) * log2(e)

// ---- converted-input float offsets in ws ----
#define I_SCTX   0
#define I_FCTX   4096
#define I_STEST  6144
#define I_OBS    10240
#define I_EW1    10248
#define I_EB1    12040
#define I_EW2    12296
#define I_EB2    28680
#define I_WQ     28744
#define I_BQ     53320
#define I_WK     53704
#define I_BK     78280
#define I_WV     78664
#define I_BV     103240
#define I_WO     103624
#define I_BO     128200
#define I_FW1    128584
#define I_FB1    177736
#define I_FW2    178504
#define I_FB2    227656
#define I_BW1    228040
#define I_BB1    228136
#define I_BW2    228232
#define I_BB2    229000
#define I_NS     229048
#define I_NB     229432
#define I_FNS    229816
#define I_FNB    229880
#define I_HW1    229944
#define I_HB1    238136
#define I_HW2    238264
#define I_HB2    238520

#define OFF_FLAG 240000
#define OFF_PW   240256    // 6 layers x 288 floats: [17][8] (slope,inter)*log2e + 16 sorted bps
#define OFF_QVS  262144
#define OFF_KVS  393216
#define OFF_Q1   524288
#define OFF_Q2   655360
#define OFF_KB   786432
#define OFF_VB   917504
#define OFF_PART 1048576   // partials: [z=4][row=1024][h=8][ks=8][12] floats (row stride 768)

__constant__ int C_OFFS[33] = {
    0, 4096, 6144, 10240, 10248, 12040, 12296, 28680, 28744, 53320, 53704,
    78280, 78664, 103240, 103624, 128200, 128584, 177736, 178504, 227656,
    228040, 228136, 228232, 229000, 229048, 229432, 229816, 229880, 229944,
    238136, 238264, 238520, 238522 };

struct InPtrs { const void* p[32]; };

__device__ __forceinline__ int get_isbf(const void* ns) {
    return (*(const unsigned*)ns == 0x3F803F80u) ? 1 : 0;
}

// ---- merged prologue: input conversion (blocks 0..255) + flag + piecewise
// bias tables (blocks 256..261). pwf reads raw inputs -> no ordering dep.
__global__ __launch_bounds__(256) void k_pre(InPtrs ptrs, float* ws) {
    const int bid = blockIdx.x, t = threadIdx.x;
    const int isbf = get_isbf(ptrs.p[24]);
    if (bid < 256) {
        const int i = bid & 31, sub = bid >> 5;
        const int o0 = C_OFFS[i], n = C_OFFS[i + 1] - o0;
        const void* src = ptrs.p[i];
        for (int j = sub * 256 + t; j < n; j += 8 * 256) {
            float v = isbf ? __bfloat162float(((const bf16*)src)[j])
                           : ((const float*)src)[j];
            ws[o0 + j] = v;
        }
        return;
    }
    // ---- piecewise tables for layer L ----
    const int L = bid - 256;
    __shared__ float w1s[16], b1s[16], bps[16];
    __shared__ int rnk[16];
    auto cv = [&](const void* p, int idx) -> float {
        return isbf ? __bfloat162float(((const bf16*)p)[idx]) : ((const float*)p)[idx];
    };
    if (t == 0 && L == 0) ((int*)(ws + OFF_FLAG))[0] = isbf;
    if (t < 16) {
        float w = cv(ptrs.p[20], L * 16 + t), b0 = cv(ptrs.p[21], L * 16 + t);
        w1s[t] = w; b1s[t] = b0;
        bps[t] = (w != 0.f) ? (-b0 / w) : 1e30f;
    }
    __syncthreads();
    if (t < 16) {
        float me = bps[t]; int r = 0;
        for (int j = 0; j < 16; ++j) {
            float o = bps[j];
            if (o < me || (o == me && j < t)) ++r;
        }
        rnk[t] = r;
    }
    __syncthreads();
    if (t < 16) ws[OFF_PW + L * 288 + 272 + rnk[t]] = bps[t];
    if (t < 136) {
        int s = t >> 3, h = t & 7;
        float slope = 0.f, inter = cv(ptrs.p[23], L * 8 + h);
        for (int j = 0; j < 16; ++j) {
            float w = w1s[j];
            bool act = (w > 0.f) ? (rnk[j] < s)
                     : (w < 0.f) ? (rnk[j] >= s)
                                 : (b1s[j] > 0.f);
            if (act) {
                float w2v = cv(ptrs.p[22], L * 128 + j * 8 + h);
                slope += w * w2v;
                inter += b1s[j] * w2v;
            }
        }
        const float LOG2E = 1.4426950408889634f;
        ws[OFF_PW + L * 288 + (s * 8 + h) * 2]     = slope * LOG2E;
        ws[OFF_PW + L * 288 + (s * 8 + h) * 2 + 1] = inter * LOG2E;
    }
}

// ---- merged embed MLP + layer-0 QKV; 2 rows per block (4 MLP instances
// share every weight read). grid 1024 x 256. Per-row math order unchanged.
__global__ __launch_bounds__(256) void k_emq(float* ws) {
    __shared__ float hbuf[4][256];    // c = lr*2 + which (0=ctx, 1=test)
    __shared__ float red[4][256];
    __shared__ float xs[4][64];
    const int r0 = blockIdx.x * 2, t = threadIdx.x;

    float in_[4][7];
#pragma unroll
    for (int lr = 0; lr < 2; ++lr) {
        int r = r0 + lr;
        const float* obc = ws + I_OBS + 4;
        const float* obu = ws + I_OBS;
        float* ic = in_[lr * 2]; float* it = in_[lr * 2 + 1];
        ic[0] = obc[0]; ic[1] = obc[1]; ic[2] = obc[2]; ic[3] = obc[3];
        it[0] = obu[0]; it[1] = obu[1]; it[2] = obu[2]; it[3] = obu[3];
        ic[4] = ws[I_SCTX + r * 2]; ic[5] = ws[I_SCTX + r * 2 + 1];
        it[4] = ws[I_STEST + r * 2]; it[5] = ws[I_STEST + r * 2 + 1];
        ic[6] = ws[I_FCTX + r]; it[6] = 0.f;
    }
    float a[4];
    {
        float b1v = ws[I_EB1 + t];
        a[0] = a[1] = a[2] = a[3] = b1v;
    }
#pragma unroll
    for (int i = 0; i < 7; ++i) {
        float w = ws[I_EW1 + i * 256 + t];
#pragma unroll
        for (int c = 0; c < 4; ++c) a[c] += in_[c][i] * w;
    }
#pragma unroll
    for (int c = 0; c < 4; ++c) hbuf[c][t] = fmaxf(a[c], 0.f);
    __syncthreads();

    {
        int d = t & 63, p = t >> 6;
        float s2[4] = {0.f, 0.f, 0.f, 0.f};
#pragma unroll 8
        for (int j = p * 64; j < p * 64 + 64; ++j) {
            float w = ws[I_EW2 + j * 64 + d];
#pragma unroll
            for (int c = 0; c < 4; ++c) s2[c] += hbuf[c][j] * w;
        }
#pragma unroll
        for (int c = 0; c < 4; ++c) red[c][t] = s2[c];
    }
    __syncthreads();
    {
        int c = t >> 6, d2 = t & 63;
        float o = red[c][d2] + red[c][64 + d2] + red[c][128 + d2]
                + red[c][192 + d2] + ws[I_EB2 + d2];
        int lr = c >> 1, which = c & 1; int r = r0 + lr;
        if (which == 0) ws[OFF_KVS + r * 64 + d2] = o;
        else            ws[OFF_QVS + r * 64 + d2] = o;
        xs[c][d2] = o;
    }
    __syncthreads();

    // layer-0 QKV: wave o4: 0=Q1(test), 1=Q2(ctx), 2=KB(ctx), 3=VB(ctx);
    // each wave projects BOTH rows (weight read shared 2x)
    {
        int o4 = t >> 6, d = t & 63;
        const float* W; const float* bbp; float* dst; int whichx;
        if (o4 == 0)      { W = ws + I_WQ; bbp = ws + I_BQ; dst = ws + OFF_Q1; whichx = 1; }
        else if (o4 == 1) { W = ws + I_WQ; bbp = ws + I_BQ; dst = ws + OFF_Q2; whichx = 0; }
        else if (o4 == 2) { W = ws + I_WK; bbp = ws + I_BK; dst = ws + OFF_KB; whichx = 0; }
        else              { W = ws + I_WV; bbp = ws + I_BV; dst = ws + OFF_VB; whichx = 0; }
        float a0 = bbp[d], a1 = a0;
#pragma unroll 8
        for (int k = 0; k < 64; ++k) {
            float w = W[k * 64 + d];
            a0 += xs[whichx][k] * w;
            a1 += xs[2 + whichx][k] * w;
        }
        dst[r0 * 64 + d]       = a0;
        dst[(r0 + 1) * 64 + d] = a1;
    }
}

// ---- attention: wave-private tiles, NO per-tile barriers (frozen R12 best) ----
// Each wave w (= ksub) owns key rows [4w, 4w+4) of every 16-key tile: it
// stages its own K/V rows, computes the bias rows for ITS keys x all 16
// queries, and the inner loop reads only its own rows. 3 barriers per block.
// grid (qt=64, ks=8, z=4); launch bounds (256,4) (proven: forcing 8 waves/EU
// collapses the allocator to 32 VGPR + 394 MB spill).
__global__ __launch_bounds__(256, 4) void k_attn(int blk, float* ws) {
    __shared__ float smem[4608];            // 18432 B
    float* Ks  = smem;                      // 16 x 68
    float* Vs  = smem + 1088;               // 16 x 68
    float* bbf = smem + 2176;               // bias [16][132] = 2112
    v2f* pw = (v2f*)(smem + 4288);          // 272 floats

    const int t = threadIdx.x;
    const int qt = blockIdx.x, ks = blockIdx.y, z = blockIdx.z;
    const int b = z & 1, kind = z >> 1;
    const int q0 = qt * 16;
    const float* Qbuf = ws + (kind == 0 ? OFF_Q1 : OFF_Q2);
    const float* Kbuf = ws + OFF_KB;
    const float* Vbuf = ws + OFF_VB;
    const float* sq_src = ws + (kind == 0 ? I_STEST : I_SCTX);
    const float* sk_src = ws + I_SCTX;
    const float* pwg = ws + OFF_PW + blk * 288;   // uniform -> scalar loads

    float bp[16];
#pragma unroll
    for (int j = 0; j < 16; ++j) bp[j] = pwg[272 + j];

    if (t < 136) pw[t] = (v2f){ pwg[t * 2], pwg[t * 2 + 1] };

    const int h    = t & 7;         // head (inner loop)
    const int qg   = (t >> 3) & 7;  // query pair (qg*2, qg*2+1) (inner loop)
    const int ksub = t >> 6;        // wave id == key quartet [4*ksub, +4)

    // Q fragments for 2 queries, resident in registers
    v2f qf[2][4];
#pragma unroll
    for (int qq = 0; qq < 2; ++qq) {
        const float* qp = Qbuf + (b * LEN + q0 + qg * 2 + qq) * 64 + h * 8;
        float4 qa = *(const float4*)qp;
        float4 qb = *(const float4*)(qp + 4);
        qf[qq][0] = (v2f){qa.x, qa.y}; qf[qq][1] = (v2f){qa.z, qa.w};
        qf[qq][2] = (v2f){qb.x, qb.y}; qf[qq][3] = (v2f){qb.z, qb.w};
    }
    // bias-phase coords: this thread handles (k = 4*ksub + (t&3), q = (t>>2)&15)
    const int kp = ksub * 4 + (t & 3);      // key row (wave-private quartet)
    const int qs = (t >> 2) & 15;           // query for bias
    float sqx, sqy;
    {
        const float* sp = sq_src + (b * LEN + q0 + qs) * 2;
        sqx = sp[0]; sqy = sp[1];
    }

    float lsum[2] = {0.f, 0.f};
    v2f oacc[2][4] = {};

    const int kt0 = ks * 8, kt1 = kt0 + 8;   // tiles of 16 keys
    const int kr = t >> 4, jc = (t & 15) * 4;   // staging coords (kr in-wave)

    // prologue: prefetch tile kt0 (K/V fragments AND key coords)
    float4 ka, va;
    float2 kc_pf;
    {
        const float* ksrc = Kbuf + (b * LEN + kt0 * 16 + kr) * 64 + jc;
        const float* vsrc = Vbuf + (b * LEN + kt0 * 16 + kr) * 64 + jc;
        ka = *(const float4*)ksrc;
        va = *(const float4*)vsrc;
        kc_pf = *(const float2*)(sk_src + (b * LEN + kt0 * 16 + kp) * 2);
    }

    __syncthreads();                  // pw table visible to all waves

    for (int kt = kt0; kt < kt1; ++kt) {
        // stage this wave's K/V rows (within-wave write->read only)
        *(float4*)&Ks[kr * 68 + jc] = ka;
        *(float4*)&Vs[kr * 68 + jc] = va;
        {   // bias precompute for wave-private keys: (kp, qs) pair
            float dx0 = sqx - kc_pf.x, dy0 = sqy - kc_pf.y;
            float d0 = dx0 * dx0 + dy0 * dy0;
            int s0 = 0;
#pragma unroll
            for (int j = 0; j < 16; ++j) s0 += (d0 > bp[j]);
            const float* p0 = (const float*)(pw + s0 * 8);   // 16 floats: sl,in x8
            float* bd0 = &bbf[kp * 132 + qs * 8];
            float4 a0 = *(const float4*)p0,       a1 = *(const float4*)(p0 + 4);
            float4 a2 = *(const float4*)(p0 + 8), a3 = *(const float4*)(p0 + 12);
            *(float4*)bd0       = make_float4(fmaf(a0.x, d0, a0.y), fmaf(a0.z, d0, a0.w),
                                              fmaf(a1.x, d0, a1.y), fmaf(a1.z, d0, a1.w));
            *(float4*)(bd0 + 4) = make_float4(fmaf(a2.x, d0, a2.y), fmaf(a2.z, d0, a2.w),
                                              fmaf(a3.x, d0, a3.y), fmaf(a3.z, d0, a3.w));
        }

        // prefetch next tile (K/V + kc; latency hides under compute below)
        if (kt + 1 < kt1) {
            const float* ksrc = Kbuf + (b * LEN + (kt + 1) * 16 + kr) * 64 + jc;
            const float* vsrc = Vbuf + (b * LEN + (kt + 1) * 16 + kr) * 64 + jc;
            ka = *(const float4*)ksrc;
            va = *(const float4*)vsrc;
            kc_pf = *(const float2*)(sk_src + (b * LEN + (kt + 1) * 16 + kp) * 2);
        }

        // inner: 4 wave-private keys; K/V frags broadcast 8-way, 2 queries each
        const float* Kb = &Ks[(ksub * 4) * 68 + h * 8];
        const float* Vb = &Vs[(ksub * 4) * 68 + h * 8];
        const float* Bb = &bbf[(ksub * 4) * 132 + qg * 16 + h];
#pragma unroll
        for (int k4 = 0; k4 < 4; ++k4) {
            const v2f* kf = (const v2f*)(Kb + k4 * 68);
            v2f k0 = kf[0], k1 = kf[1], k2v = kf[2], k3 = kf[3];
            const v2f* vf = (const v2f*)(Vb + k4 * 68);
            v2f v0 = vf[0], v1 = vf[1], v2v = vf[2], v3 = vf[3];
#pragma unroll
            for (int qq = 0; qq < 2; ++qq) {
                float bv = Bb[k4 * 132 + qq * 8];
                v2f a = qf[qq][0] * k0;
                a += qf[qq][1] * k1;
                a += qf[qq][2] * k2v;
                a += qf[qq][3] * k3;
                float sv = fmaf(a.x + a.y, SCALE_L2E, bv);
                float p = exp2f(sv);
                lsum[qq] += p;
                v2f pp = (v2f){p, p};
                oacc[qq][0] += pp * v0;
                oacc[qq][1] += pp * v1;
                oacc[qq][2] += pp * v2v;
                oacc[qq][3] += pp * v3;
            }
        }
    }

    // merge 4 ksub waves via LDS overlay (aliases everything), write partial
    __syncthreads();
    if (ksub) {
#pragma unroll
        for (int qq = 0; qq < 2; ++qq) {
            float* p = &smem[(((ksub - 1) * 16 + qg * 2 + qq) * 8 + h) * 12];
            *(float4*)p       = make_float4(oacc[qq][0].x, oacc[qq][0].y, oacc[qq][1].x, oacc[qq][1].y);
            *(float4*)(p + 4) = make_float4(oacc[qq][2].x, oacc[qq][2].y, oacc[qq][3].x, oacc[qq][3].y);
            p[8] = lsum[qq];
        }
    }
    __syncthreads();
    if (ksub == 0) {
#pragma unroll
        for (int qq = 0; qq < 2; ++qq) {
            int q = qg * 2 + qq;
            float ov[8] = { oacc[qq][0].x, oacc[qq][0].y, oacc[qq][1].x, oacc[qq][1].y,
                            oacc[qq][2].x, oacc[qq][2].y, oacc[qq][3].x, oacc[qq][3].y };
            float lq = lsum[qq];
#pragma unroll
            for (int m = 0; m < 3; ++m) {
                const float* p = &smem[((m * 16 + q) * 8 + h) * 12];
                float4 m0 = *(const float4*)p, m1 = *(const float4*)(p + 4);
                ov[0] += m0.x; ov[1] += m0.y; ov[2] += m0.z; ov[3] += m0.w;
                ov[4] += m1.x; ov[5] += m1.y; ov[6] += m1.z; ov[7] += m1.w;
                lq += p[8];
            }
            float* pp = ws + OFF_PART + (z * LEN + q0 + q) * 768 + (h * 8 + ks) * 12;
            *(float4*)(pp)     = make_float4(ov[0], ov[1], ov[2], ov[3]);
            *(float4*)(pp + 4) = make_float4(ov[4], ov[5], ov[6], ov[7]);
            *(float4*)(pp + 8) = make_float4(lq, 0.f, 0.f, 0.f);
        }
    }
}

// ---- fused: partial-merge + Wo + LN + FFN + LN + next-QKV (+head on last) ----
// 4 rows per 256-thread block: wave w = row w for wave-per-row phases;
// FFN/head hidden and Q2/KB/VB share weight reads across rows.
// grid (bx=512, kind=2).
__global__ __launch_bounds__(256) void k_fuse(int blk, float* ws, void* out_raw) {
    __shared__ float raw[3072];       // 4 rows x 768
    __shared__ float xo[4][64];
    __shared__ float xs[4][64];
    __shared__ float hs[4][128];
    __shared__ float xn[4][64];
    __shared__ int sflag;
    const int bx = blockIdx.x, kind = blockIdx.y, t = threadIdx.x;
    const int r0 = bx * 4;            // rows r0..r0+3 (same b: 1024 % 4 == 0)
    const int b = r0 >> 10, row0 = r0 & 1023;
    const int z = kind * 2 + b;
    const int w = t >> 6, tt = t & 63;   // wave w handles row r0+w in per-row phases
    float* io = ws + (kind == 0 ? OFF_QVS : OFF_KVS);

    const float* pbase = ws + OFF_PART + (z * LEN + row0) * 768;  // 4 rows contiguous
    for (int i = t; i < 768; i += 256) *(float4*)&raw[i * 4] = *(const float4*)&pbase[i * 4];
    __syncthreads();

    // merge 8 K-split partials per (row=w, h, d): plain sums (256 lanes = 4x64)
    {
        int h = tt >> 3, d = tt & 7;
        const float* rw = raw + w * 768;
        float L = 0.f, o = 0.f;
#pragma unroll
        for (int k2 = 0; k2 < 8; ++k2) {
            L += rw[(h * 8 + k2) * 12 + 8];
            o += rw[(h * 8 + k2) * 12 + d];
        }
        xo[w][tt] = o / L;
    }
    __syncthreads();

    // Wo projection + residual + LN; wave per row
    {
        const float* Wo = ws + I_WO + blk * 4096;
        float acc = ws[I_BO + blk * 64 + tt];
#pragma unroll 8
        for (int j = 0; j < 64; ++j) acc += xo[w][j] * Wo[j * 64 + tt];
        acc += io[(r0 + w) * 64 + tt];
        float s = acc, ss2 = acc * acc;
#pragma unroll
        for (int off = 1; off < 64; off <<= 1) { s += __shfl_xor(s, off); ss2 += __shfl_xor(ss2, off); }
        float mu_ = s * (1.f / 64.f);
        float var_ = ss2 * (1.f / 64.f) - mu_ * mu_;
        float rs_ = rsqrtf(fmaxf(var_, 0.f) + 1e-6f);
        xs[w][tt] = (acc - mu_) * rs_ * ws[I_NS + blk * 64 + tt] + ws[I_NB + blk * 64 + tt];
    }
    __syncthreads();

    // FFN hidden: col = t&127, row pair rp = t>>7 (weight read shared 2x)
    {
        int col = t & 127, rp = (t >> 7) * 2;
        const float* W1 = ws + I_FW1 + blk * 8192;
        float a0 = ws[I_FB1 + blk * 128 + col], a1 = a0;
#pragma unroll 8
        for (int k = 0; k < 64; ++k) {
            float wv = W1[k * 128 + col];
            a0 += xs[rp][k] * wv;
            a1 += xs[rp + 1][k] * wv;
        }
        hs[rp][col]     = fmaxf(a0, 0.f);
        hs[rp + 1][col] = fmaxf(a1, 0.f);
    }
    __syncthreads();

    // FFN out + residual + LN -> new layer state; wave per row
    {
        const float* W2 = ws + I_FW2 + blk * 8192;
        float a2 = ws[I_FB2 + blk * 64 + tt];
#pragma unroll 8
        for (int k = 0; k < 128; ++k) a2 += hs[w][k] * W2[k * 64 + tt];
        a2 += xs[w][tt];
        float s = a2, ss2 = a2 * a2;
#pragma unroll
        for (int off = 1; off < 64; off <<= 1) { s += __shfl_xor(s, off); ss2 += __shfl_xor(ss2, off); }
        float mu_ = s * (1.f / 64.f);
        float var_ = ss2 * (1.f / 64.f) - mu_ * mu_;
        float rs_ = rsqrtf(fmaxf(var_, 0.f) + 1e-6f);
        float outv = (a2 - mu_) * rs_ * ws[I_NS + blk * 64 + tt] + ws[I_NB + blk * 64 + tt];
        io[(r0 + w) * 64 + tt] = outv;
        xn[w][tt] = outv;
    }
    __syncthreads();

    if (blk < 5) {   // next-layer QKV projection
        const int nb_ = blk + 1;
        if (kind == 0) {
            // Q1: wave per row
            const float* W = ws + I_WQ + nb_ * 4096;
            float acc = ws[I_BQ + nb_ * 64 + tt];
#pragma unroll 8
            for (int k = 0; k < 64; ++k) acc += xn[w][k] * W[k * 64 + tt];
            ws[OFF_Q1 + (r0 + w) * 64 + tt] = acc;
        } else {
            if (w < 2) {
                // w0: Q2 all 4 rows; w1: KB all 4 rows (weight read shared 4x)
                const float* W  = ws + (w == 0 ? I_WQ : I_WK) + nb_ * 4096;
                const float* bbp = ws + (w == 0 ? I_BQ : I_BK) + nb_ * 64;
                float* dst = ws + (w == 0 ? OFF_Q2 : OFF_KB);
                float a0 = bbp[tt], a1 = a0, a2 = a0, a3 = a0;
#pragma unroll 8
                for (int k = 0; k < 64; ++k) {
                    float wv = W[k * 64 + tt];
                    a0 += xn[0][k] * wv;
                    a1 += xn[1][k] * wv;
                    a2 += xn[2][k] * wv;
                    a3 += xn[3][k] * wv;
                }
                dst[(r0 + 0) * 64 + tt] = a0;
                dst[(r0 + 1) * 64 + tt] = a1;
                dst[(r0 + 2) * 64 + tt] = a2;
                dst[(r0 + 3) * 64 + tt] = a3;
            } else {
                // w2: VB rows 0-1; w3: VB rows 2-3 (weight read shared 2x)
                int rb = (w - 2) * 2;
                const float* Wv = ws + I_WV + nb_ * 4096;
                float a0 = ws[I_BV + nb_ * 64 + tt], a1 = a0;
#pragma unroll 8
                for (int k = 0; k < 64; ++k) {
                    float wv = Wv[k * 64 + tt];
                    a0 += xn[rb][k] * wv;
                    a1 += xn[rb + 1][k] * wv;
                }
                ws[OFF_VB + (r0 + rb) * 64 + tt]     = a0;
                ws[OFF_VB + (r0 + rb + 1) * 64 + tt] = a1;
            }
        }
    } else if (kind == 0) {
        // ---- inline head for rows r0..r0+3 (xn holds final qvs) ----
        if (t == 0) sflag = ((const int*)(ws + OFF_FLAG))[0];
        // final LN per row (wave per row), into xo
        {
            float v = xn[w][tt];
            float s = v, ss2 = v * v;
#pragma unroll
            for (int off = 1; off < 64; off <<= 1) { s += __shfl_xor(s, off); ss2 += __shfl_xor(ss2, off); }
            float mu_ = s * (1.f / 64.f);
            float var_ = ss2 * (1.f / 64.f) - mu_ * mu_;
            float rs_ = rsqrtf(fmaxf(var_, 0.f) + 1e-6f);
            xo[w][tt] = (v - mu_) * rs_ * ws[I_FNS + tt] + ws[I_FNB + tt];
        }
        __syncthreads();
        // head hidden: col = t&127, row pair rp = t>>7 (weight shared 2x)
        {
            int col = t & 127, rp = (t >> 7) * 2;
            float a0 = ws[I_HB1 + col], a1 = a0;
#pragma unroll 8
            for (int k = 0; k < 64; ++k) {
                float wv = ws[I_HW1 + k * 128 + col];
                a0 += xo[rp][k] * wv;
                a1 += xo[rp + 1][k] * wv;
            }
            hs[rp][col]     = fmaxf(a0, 0.f);
            hs[rp + 1][col] = fmaxf(a1, 0.f);
        }
        __syncthreads();
        if (t < 8) {
            int row = t >> 1, c = t & 1;
            float a = ws[I_HB2 + c];
            for (int j = 0; j < 128; ++j) a += hs[row][j] * ws[I_HW2 + j * 2 + c];
            float v = (c == 0) ? a : __expf(a * 0.5f);
            int r = r0 + row;
            int idx = (c == 0) ? r : (N2 + r);
            if (sflag) ((bf16*)out_raw)[idx] = __float2bfloat16(v);
            else       ((float*)out_raw)[idx] = v;
        }
    }
}

extern "C" void kernel_launch(void* const* d_in, const int* in_sizes, int n_in,
                              void* d_out, int out_size, void* d_ws, size_t ws_size,
                              hipStream_t stream) {
    float* ws = (float*)d_ws;

    InPtrs ptrs;
    for (int i = 0; i < 32; ++i) ptrs.p[i] = d_in[i];

    k_pre<<<262, 256, 0, stream>>>(ptrs, ws);                 // cvt + flag + pw tables
    k_emq<<<1024, 256, 0, stream>>>(ws);                      // embed + layer-0 QKV (2 rows/blk)
    for (int i = 0; i < 6; ++i) {
        k_attn<<<dim3(64, 8, 4), 256, 0, stream>>>(i, ws);
        k_fuse<<<dim3(512, 2), 256, 0, stream>>>(i, ws, d_out);  // 4 rows/blk; head on i=5
    }
}